// Round 11
// baseline (596.400 us; speedup 1.0000x reference)
//
#include <hip/hip_runtime.h>
#include <hip/hip_bf16.h>
#include <math.h>

// ---- problem constants ----
#define BB 64
#define NN 128
#define DD 512
#define DFF 2048
#define HH 8
#define DHH 64
#define EE 32
#define HID 64
#define LL 4
#define NTOK (BB*NN)          // 8192
#define LDQKV 1536

typedef __hip_bfloat16 bf16;
typedef __attribute__((ext_vector_type(8))) short short8v;   // 8 bf16 (4 VGPRs)
typedef __attribute__((ext_vector_type(4))) float f32x4v;    // 4 f32 acc

__device__ __forceinline__ float b2f(bf16 x) { return __bfloat162float(x); }
__device__ __forceinline__ bf16 f2b(float x) { return __float2bfloat16(x); }
__device__ __forceinline__ float gelu_f(float x) {
    return 0.5f * x * (1.0f + erff(x * 0.7071067811865476f));
}
// async global->LDS, 16B/lane; LDS dest is wave-uniform base + lane*16
__device__ __forceinline__ void glds16(const bf16* g, bf16* l) {
    __builtin_amdgcn_global_load_lds(
        (const __attribute__((address_space(1))) unsigned int*)g,
        (__attribute__((address_space(3))) unsigned int*)l,
        16, 0, 0);
}

union F4B8 { float4 f; bf16 h[8]; };
union B2U { bf16 h[2]; unsigned int u; };

// ---------------- merged weight prep: 8 transpose jobs in one launch -------
#define NJOBS 8
struct TXJobs {
    const float* in[NJOBS];
    bf16* out[NJOBS];
    int K[NJOBS], N[NJOBS];
    long long sIn[NJOBS], sOut[NJOBS];
    int tileEnd[NJOBS];          // inclusive prefix sum of G*(K/32)*(N/32)
};
__global__ __launch_bounds__(256) void transpose_all(TXJobs jobs)
{
    __shared__ float t[32][33];
    int tile = blockIdx.x;
    int j = 0;
    while (j < NJOBS - 1 && tile >= jobs.tileEnd[j]) ++j;
    int base = j ? jobs.tileEnd[j-1] : 0;
    int local = tile - base;
    const int K = jobs.K[j], N = jobs.N[j];
    const int tpg = (K >> 5) * (N >> 5);
    int g  = local / tpg;
    int r  = local % tpg;
    int tX = r % (N >> 5), tY = r / (N >> 5);
    const float* in = jobs.in[j] + (size_t)g * jobs.sIn[j];
    bf16* out = jobs.out[j] + (size_t)g * jobs.sOut[j];
    int n0 = tX * 32, k0 = tY * 32;
    int tx = threadIdx.x & 31, ty = threadIdx.x >> 5;
#pragma unroll
    for (int i = 0; i < 32; i += 8)
        t[ty + i][tx] = in[(size_t)(k0 + ty + i) * N + n0 + tx];
    __syncthreads();
#pragma unroll
    for (int i = 0; i < 32; i += 8)
        out[(size_t)(n0 + ty + i) * K + k0 + tx] = f2b(t[tx][ty + i]);
}

// merged bias packing: qkvB [L][1536] then dagB [1024]
__global__ __launch_bounds__(256) void pack_bias(
    const float* __restrict__ bq, const float* __restrict__ bk,
    const float* __restrict__ bv, const float* __restrict__ dp,
    const float* __restrict__ dc, float* __restrict__ qkvB,
    float* __restrict__ dagB)
{
    int i = blockIdx.x * 256 + threadIdx.x;
    if (i < LL * LDQKV) {
        int l = i / LDQKV, j = i % LDQKV;
        float v = (j < 512) ? bq[l*512 + j]
                : (j < 1024 ? bk[l*512 + j - 512] : bv[l*512 + j - 1024]);
        qkvB[i] = v;
    } else if (i < LL * LDQKV + 1024) {
        int j = i - LL * LDQKV;
        dagB[j] = (j < 512) ? dp[j] : dc[j - 512];
    }
}

// ---------------- encoder ----------------
__global__ __launch_bounds__(256) void encoder_kernel(
    const float* __restrict__ bs, const float* __restrict__ ins,
    const float* __restrict__ tr, const float* __restrict__ im,
    const float* __restrict__ encW, const float* __restrict__ encB,
    bf16* __restrict__ X)
{
    int idx = blockIdx.x * 256 + threadIdx.x;
    size_t i8 = (size_t)idx * 8;
    int d0 = (int)(i8 & (DD - 1));
    int t  = (int)(i8 >> 9);
    float f0 = bs[t], f1 = ins[t], f2 = tr[t], f3 = im[t];
    alignas(16) float acc[8], w[8];
    *(float4*)&acc[0] = *(const float4*)&encB[d0];
    *(float4*)&acc[4] = *(const float4*)&encB[d0 + 4];
    const float fs[4] = {f0, f1, f2, f3};
#pragma unroll
    for (int k = 0; k < 4; k++) {
        *(float4*)&w[0] = *(const float4*)&encW[k * DD + d0];
        *(float4*)&w[4] = *(const float4*)&encW[k * DD + d0 + 4];
#pragma unroll
        for (int j = 0; j < 8; j++) acc[j] = fmaf(fs[k], w[j], acc[j]);
    }
    F4B8 o;
#pragma unroll
    for (int j = 0; j < 8; j++) o.h[j] = f2b(acc[j]);
    *(float4*)&X[i8] = o.f;
}

// ---------------- MFMA GEMM ----------------
// TRANSB (bf16 [N][K]): glds direct staging, pre-swizzled source, linear LDS,
//   3-buffer 2-deep prefetch with counted vmcnt + raw s_barrier (T3/T4).
// !TRANSB (f32 [K][N]): reg-staged dbuf with transpose+cvt (expert GEMM);
//   ASCALE multiplies A by modp[row*DD + k] during commit (fused xm).
// FUSE_ADJ: epilogue also writes adj = sigmoid(C + gn) (logits GEMM).
template<int BM,int BN,int WM,int WN,int ACT,bool TRANSB,bool HAS_BIAS,
         bool ASCALE,bool FUSE_ADJ,typename TB,typename TC>
__global__ __launch_bounds__(WM*WN*64) void gemm2(
    const bf16* __restrict__ A, const TB* __restrict__ Bw,
    const float* __restrict__ bias, TC* __restrict__ C,
    int K, int lda, int ldb, int ldc,
    long long sAg, long long sBg, long long sbg, long long sCg,
    const float* __restrict__ modp, const float* __restrict__ gn,
    float* __restrict__ adjout)
{
    constexpr int BK = 64;
    constexpr int NT = WM*WN*64;
    constexpr int NW = NT/64;
    constexpr int MI = BM/WM/16;
    constexpr int NI = BN/WN/16;
    constexpr int LDK = TRANSB ? BK : (BK + 8);
    constexpr int NBUF = TRANSB ? 3 : 2;
    constexpr int LDC = BN + 8;
    constexpr size_t SH_AB = (size_t)NBUF*(BM+BN)*LDK*sizeof(bf16);
    constexpr size_t SH_C  = (size_t)BM*LDC*sizeof(TC);
    __shared__ __align__(16) char smem[(SH_AB > SH_C ? SH_AB : SH_C)];
    bf16* AsB = (bf16*)smem;                      // [NBUF][BM][LDK]
    bf16* BsB = AsB + (size_t)NBUF*BM*LDK;        // [NBUF][BN][LDK]
    TC*   Cs  = (TC*)smem;                        // [BM][LDC]

    const int g = blockIdx.z;
    const bf16* Ag = A + (size_t)g * sAg;
    const TB*   Bg = Bw + (size_t)g * sBg;

    // XCD-chunked swizzle (bijective when nwg % 8 == 0; skip grouped)
    int bx = blockIdx.x, by = blockIdx.y;
    if (gridDim.z == 1) {
        int nwg = gridDim.x * gridDim.y;
        if ((nwg & 7) == 0) {
            int id = by * gridDim.x + bx;
            id = (id & 7) * (nwg >> 3) + (id >> 3);
            bx = id % gridDim.x;
            by = id / gridDim.x;
        }
    }
    const int m0 = by * BM, n0 = bx * BN;
    const int tid = threadIdx.x, lane = tid & 63, wid = tid >> 6;
    const int wm = wid / WN, wn = wid % WN;
    const int lr = lane & 15, lq = lane >> 4;
    const int KT = K / BK;

    f32x4v acc[MI][NI];
#pragma unroll
    for (int mi = 0; mi < MI; mi++)
#pragma unroll
        for (int ni = 0; ni < NI; ni++)
            acc[mi][ni] = (f32x4v){0.f, 0.f, 0.f, 0.f};

    if constexpr (TRANSB) {
        // glds per wave per stage (uniform across waves)
        constexpr int GL = (BM/8 + BN/8) / NW;
        auto stage = [&](int kt, int p) {
#pragma unroll
            for (int q = wid; q < BM/8; q += NW) {
                int r = q*8 + (lane >> 3), sp = lane & 7;
                glds16(Ag + (size_t)(m0 + r)*lda + kt*BK + ((sp ^ (r & 7)) << 3),
                       AsB + ((size_t)p*BM + q*8)*BK);
            }
#pragma unroll
            for (int q = wid; q < BN/8; q += NW) {
                int r = q*8 + (lane >> 3), sp = lane & 7;
                glds16((const bf16*)Bg + (size_t)(n0 + r)*ldb + kt*BK + ((sp ^ (r & 7)) << 3),
                       BsB + ((size_t)p*BN + q*8)*BK);
            }
        };
        stage(0, 0);
        if (KT > 1) {
            stage(1, 1);
            asm volatile("s_waitcnt vmcnt(%0)" :: "n"(GL) : "memory");
        } else {
            asm volatile("s_waitcnt vmcnt(0)" ::: "memory");
        }
        __builtin_amdgcn_s_barrier();
        __builtin_amdgcn_sched_barrier(0);
        const int rx7 = lr & 7;
        for (int kt = 0; kt < KT; ++kt) {
            const int p = kt % 3;
            if (kt + 2 < KT) stage(kt + 2, (kt + 2) % 3);  // 2-deep prefetch
#pragma unroll
            for (int kk = 0; kk < 2; ++kk) {
                const int colo = ((((kk << 2) | lq) ^ rx7) << 3);
                short8v av[MI], bv[NI];
#pragma unroll
                for (int mi = 0; mi < MI; ++mi) {
                    int row = wm*(BM/WM) + mi*16 + lr;
                    av[mi] = *(const short8v*)&AsB[((size_t)p*BM + row)*BK + colo];
                }
#pragma unroll
                for (int ni = 0; ni < NI; ++ni) {
                    int row = wn*(BN/WN) + ni*16 + lr;
                    bv[ni] = *(const short8v*)&BsB[((size_t)p*BN + row)*BK + colo];
                }
#pragma unroll
                for (int mi = 0; mi < MI; ++mi)
#pragma unroll
                    for (int ni = 0; ni < NI; ++ni)
                        acc[mi][ni] = __builtin_amdgcn_mfma_f32_16x16x32_bf16(
                            av[mi], bv[ni], acc[mi][ni], 0, 0, 0);
            }
            if (kt + 1 < KT) {
                // next buffer must be resident; newest stage stays in flight
                if (kt + 2 < KT)
                    asm volatile("s_waitcnt vmcnt(%0)" :: "n"(GL) : "memory");
                else
                    asm volatile("s_waitcnt vmcnt(0)" ::: "memory");
                __builtin_amdgcn_s_barrier();
                __builtin_amdgcn_sched_barrier(0);
            }
        }
    } else {
        // ---- f32-B path: reg-staged dbuf with transpose+cvt ----
        constexpr int RA  = (BM*(BK/8))/NT;
        constexpr int RBF = (BK*(BN/4))/NT;
        float4 rA[RA];
        float4 rF[RBF];
        int staged_kt = 0;
        auto issue = [&](int kt) {
            staged_kt = kt;
#pragma unroll
            for (int r = 0; r < RA; ++r) {
                int c = tid + r*NT; int row = c >> 3, k8 = (c & 7) << 3;
                rA[r] = *(const float4*)(Ag + (size_t)(m0+row)*lda + kt*BK + k8);
            }
#pragma unroll
            for (int r = 0; r < RBF; ++r) {
                int c = tid + r*NT; int kk = c/(BN/4), n4 = (c%(BN/4))*4;
                rF[r] = *(const float4*)((const float*)Bg + (size_t)(kt*BK+kk)*ldb + n0 + n4);
            }
        };
        auto commit = [&](int p) {
#pragma unroll
            for (int r = 0; r < RA; ++r) {
                int c = tid + r*NT; int row = c >> 3, k8 = (c & 7) << 3;
                if constexpr (ASCALE) {
                    F4B8 u; u.f = rA[r];
                    alignas(16) float m8[8];
                    const float* mp = modp + (size_t)(m0+row)*DD + staged_kt*BK + k8;
                    *(float4*)&m8[0] = *(const float4*)mp;
                    *(float4*)&m8[4] = *(const float4*)(mp + 4);
#pragma unroll
                    for (int jj = 0; jj < 8; ++jj)
                        u.h[jj] = f2b(b2f(u.h[jj]) * m8[jj]);
                    *(float4*)&AsB[((size_t)p*BM + row)*LDK + k8] = u.f;
                } else {
                    *(float4*)&AsB[((size_t)p*BM + row)*LDK + k8] = rA[r];
                }
            }
#pragma unroll
            for (int r = 0; r < RBF; ++r) {
                int c = tid + r*NT; int kk = c/(BN/4), n4 = (c%(BN/4))*4;
                int kg = kk >> 3, kw = kk & 7;
                alignas(16) float vv[4]; *(float4*)vv = rF[r];
#pragma unroll
                for (int i = 0; i < 4; ++i) {
                    int n = n4 + i;
                    BsB[((size_t)p*BN + n)*LDK + (((kg ^ ((n>>2)&7)) << 3) | kw)] = f2b(vv[i]);
                }
            }
        };
        issue(0); commit(0); __syncthreads();
        for (int kt = 0; kt < KT; ++kt) {
            if (kt + 1 < KT) issue(kt + 1);
            const int p = kt & 1;
#pragma unroll
            for (int kk = 0; kk < 2; ++kk) {
                short8v av[MI], bv[NI];
#pragma unroll
                for (int mi = 0; mi < MI; ++mi) {
                    int row = wm*(BM/WM) + mi*16 + lr;
                    av[mi] = *(const short8v*)&AsB[((size_t)p*BM + row)*LDK + kk*32 + lq*8];
                }
#pragma unroll
                for (int ni = 0; ni < NI; ++ni) {
                    int row = wn*(BN/WN) + ni*16 + lr;
                    int col = (((kk*4 + lq) ^ ((row>>2)&7)) << 3);
                    bv[ni] = *(const short8v*)&BsB[((size_t)p*BN + row)*LDK + col];
                }
#pragma unroll
                for (int mi = 0; mi < MI; ++mi)
#pragma unroll
                    for (int ni = 0; ni < NI; ++ni)
                        acc[mi][ni] = __builtin_amdgcn_mfma_f32_16x16x32_bf16(
                            av[mi], bv[ni], acc[mi][ni], 0, 0, 0);
            }
            if (kt + 1 < KT) { commit((kt + 1) & 1); }
            __syncthreads();
        }
    }
    __syncthreads();     // full drain; safe to reuse smem as C tile

    // stage C (bias + act) into LDS
#pragma unroll
    for (int mi = 0; mi < MI; ++mi) {
        int rb = wm*(BM/WM) + mi*16 + lq*4;
#pragma unroll
        for (int ni = 0; ni < NI; ++ni) {
            int cc = wn*(BN/WN) + ni*16 + lr;
            float bvv = 0.f;
            if constexpr (HAS_BIAS) bvv = bias[(size_t)g*sbg + n0 + cc];
#pragma unroll
            for (int r = 0; r < 4; ++r) {
                float v = acc[mi][ni][r] + bvv;
                if (ACT == 1) v = gelu_f(v);
                if constexpr (sizeof(TC) == 2) Cs[(rb+r)*LDC + cc] = (TC)f2b(v);
                else ((float*)Cs)[(rb+r)*LDC + cc] = v;
            }
        }
    }
    __syncthreads();

    // coalesced vector store: 16B per lane (+ optional fused adj)
    constexpr int VEC = 16 / sizeof(TC);
#pragma unroll
    for (int c = tid; c < BM*(BN/VEC); c += NT) {
        int row = c / (BN/VEC), col = (c % (BN/VEC)) * VEC;
        size_t gidx = (size_t)g*sCg + (size_t)(m0+row)*ldc + n0 + col;
        *(float4*)&C[gidx] = *(const float4*)&Cs[row*LDC + col];
        if constexpr (FUSE_ADJ) {
            float4 cv = *(const float4*)&Cs[row*LDC + col];
            float4 g4 = *(const float4*)&gn[gidx];
            float4 a4;
            a4.x = 1.0f / (1.0f + __expf(-(cv.x + g4.x)));
            a4.y = 1.0f / (1.0f + __expf(-(cv.y + g4.y)));
            a4.z = 1.0f / (1.0f + __expf(-(cv.z + g4.z)));
            a4.w = 1.0f / (1.0f + __expf(-(cv.w + g4.w)));
            *(float4*)&adjout[gidx] = a4;
        }
    }
}

// ---------------- MFMA fused attention on packed QKV [8192][1536] ----------
__global__ __launch_bounds__(256) void attn_mfma(bf16* __restrict__ QKV)
{
    __shared__ bf16 Ps[NN][NN + 8];
    __shared__ bf16 Vt[DHH][NN + 8];
    int bh = blockIdx.x;
    int h = bh & (HH - 1);
    int b = bh >> 3;
    const int tid = threadIdx.x;
    const int lane = tid & 63;
    const int w = tid >> 6;
    const int lr = lane & 15;
    const int lq = lane >> 4;
    const size_t baseQ = (size_t)(b * NN) * LDQKV + h * DHH;
    const size_t baseK = baseQ + 512;
    const size_t baseV = baseQ + 1024;

    for (int c = tid; c < 512; c += 256) {
        int m = (c >> 3) * 2;
        int d8 = (c & 7) * 8;
        F4B8 v0, v1;
        v0.f = *(const float4*)(QKV + baseV + (size_t)m * LDQKV + d8);
        v1.f = *(const float4*)(QKV + baseV + (size_t)(m + 1) * LDQKV + d8);
#pragma unroll
        for (int j = 0; j < 8; j++) {
            B2U pk; pk.h[0] = v0.h[j]; pk.h[1] = v1.h[j];
            *(unsigned int*)&Vt[d8 + j][m] = pk.u;
        }
    }

    f32x4v sacc[2][8];
#pragma unroll
    for (int mi = 0; mi < 2; mi++)
#pragma unroll
        for (int ni = 0; ni < 8; ni++)
            sacc[mi][ni] = (f32x4v){0.f, 0.f, 0.f, 0.f};
#pragma unroll
    for (int ks = 0; ks < 2; ks++) {
        short8v aq[2];
#pragma unroll
        for (int mi = 0; mi < 2; mi++) {
            int row = w * 32 + mi * 16 + lr;
            aq[mi] = *(const short8v*)(QKV + baseQ + (size_t)row * LDQKV + ks * 32 + lq * 8);
        }
#pragma unroll
        for (int ni = 0; ni < 8; ni++) {
            int col = ni * 16 + lr;
            short8v bk = *(const short8v*)(QKV + baseK + (size_t)col * LDQKV + ks * 32 + lq * 8);
#pragma unroll
            for (int mi = 0; mi < 2; mi++)
                sacc[mi][ni] = __builtin_amdgcn_mfma_f32_16x16x32_bf16(
                    aq[mi], bk, sacc[mi][ni], 0, 0, 0);
        }
    }

#pragma unroll
    for (int mi = 0; mi < 2; mi++) {
#pragma unroll
        for (int r = 0; r < 4; r++) {
            float mx = -1e30f;
#pragma unroll
            for (int ni = 0; ni < 8; ni++)
                mx = fmaxf(mx, sacc[mi][ni][r]);
            mx = fmaxf(mx, __shfl_xor(mx, 1, 64));
            mx = fmaxf(mx, __shfl_xor(mx, 2, 64));
            mx = fmaxf(mx, __shfl_xor(mx, 4, 64));
            mx = fmaxf(mx, __shfl_xor(mx, 8, 64));
            mx *= 0.125f;
            float s = 0.f;
#pragma unroll
            for (int ni = 0; ni < 8; ni++) {
                float e = __expf(sacc[mi][ni][r] * 0.125f - mx);
                sacc[mi][ni][r] = e; s += e;
            }
            s += __shfl_xor(s, 1, 64);
            s += __shfl_xor(s, 2, 64);
            s += __shfl_xor(s, 4, 64);
            s += __shfl_xor(s, 8, 64);
            float inv = 1.0f / s;
            int row = w * 32 + mi * 16 + lq * 4 + r;
#pragma unroll
            for (int ni = 0; ni < 8; ni++)
                Ps[row][ni * 16 + lr] = f2b(sacc[mi][ni][r] * inv);
        }
    }
    __syncthreads();

    f32x4v oacc[2][4];
#pragma unroll
    for (int mi = 0; mi < 2; mi++)
#pragma unroll
        for (int ni = 0; ni < 4; ni++)
            oacc[mi][ni] = (f32x4v){0.f, 0.f, 0.f, 0.f};
#pragma unroll
    for (int ks = 0; ks < 4; ks++) {
        short8v ap[2];
#pragma unroll
        for (int mi = 0; mi < 2; mi++)
            ap[mi] = *(const short8v*)&Ps[w * 32 + mi * 16 + lr][ks * 32 + lq * 8];
#pragma unroll
        for (int ni = 0; ni < 4; ni++) {
            short8v bv = *(const short8v*)&Vt[ni * 16 + lr][ks * 32 + lq * 8];
#pragma unroll
            for (int mi = 0; mi < 2; mi++)
                oacc[mi][ni] = __builtin_amdgcn_mfma_f32_16x16x32_bf16(
                    ap[mi], bv, oacc[mi][ni], 0, 0, 0);
        }
    }
    __syncthreads();           // Ps fragment reads done — reuse Ps as O tile
#pragma unroll
    for (int mi = 0; mi < 2; mi++)
#pragma unroll
        for (int ni = 0; ni < 4; ni++) {
            int d = ni * 16 + lr;
#pragma unroll
            for (int r = 0; r < 4; r++) {
                int row = w * 32 + mi * 16 + lq * 4 + r;
                Ps[row][d] = f2b(oacc[mi][ni][r]);
            }
        }
    __syncthreads();
    for (int c = tid; c < NN * (DHH/8); c += 256) {
        int row = c >> 3, d8 = (c & 7) * 8;
        *(float4*)(QKV + baseQ + (size_t)row * LDQKV + d8) = *(const float4*)&Ps[row][d8];
    }
}

// ---------------- add+LN: one wave per token; R has stride ldr ------------
__global__ __launch_bounds__(256) void add_ln_kernel(
    bf16* __restrict__ X, const bf16* __restrict__ R, int ldr,
    const float* __restrict__ g, const float* __restrict__ bt)
{
    int tok = blockIdx.x * 4 + (threadIdx.x >> 6);
    int lane = threadIdx.x & 63;
    size_t base = (size_t)tok * DD + lane * 8;
    size_t rbase = (size_t)tok * ldr + lane * 8;
    F4B8 x, r;
    x.f = *(const float4*)&X[base];
    r.f = *(const float4*)&R[rbase];
    float v[8]; float s = 0.f, s2 = 0.f;
#pragma unroll
    for (int j = 0; j < 8; j++) {
        v[j] = b2f(x.h[j]) + b2f(r.h[j]);
        s += v[j]; s2 += v[j] * v[j];
    }
#pragma unroll
    for (int m = 1; m < 64; m <<= 1) {
        s  += __shfl_xor(s, m, 64);
        s2 += __shfl_xor(s2, m, 64);
    }
    float mean = s * (1.0f / 512.0f);
    float var = fmaxf(s2 * (1.0f / 512.0f) - mean * mean, 0.0f);
    float rstd = rsqrtf(var + 1e-5f);
    alignas(16) float gv[8], bv[8];
    *(float4*)&gv[0] = *(const float4*)&g[lane * 8];
    *(float4*)&gv[4] = *(const float4*)&g[lane * 8 + 4];
    *(float4*)&bv[0] = *(const float4*)&bt[lane * 8];
    *(float4*)&bv[4] = *(const float4*)&bt[lane * 8 + 4];
    F4B8 o;
#pragma unroll
    for (int j = 0; j < 8; j++)
        o.h[j] = f2b((v[j] - mean) * rstd * gv[j] + bv[j]);
    *(float4*)&X[base] = o.f;
}

// ---------------- hyper-network ----------------
__global__ __launch_bounds__(512) void hyper_kernel(
    const int* __restrict__ idx, const float* __restrict__ emb,
    const float* __restrict__ W1, const float* __restrict__ b1,
    const float* __restrict__ W2, const float* __restrict__ b2,
    float* __restrict__ MODp)
{
    int b = blockIdx.x;
    int t = threadIdx.x;
    __shared__ float instr[EE];
    __shared__ float h1[HID];
    int id = idx[b];
    if (t < EE) instr[t] = emb[id*EE + t];
    __syncthreads();
    if (t < HID) {
        float a = b1[t];
        for (int i = 0; i < EE; i++) a += instr[i] * W1[i*HID + t];
        h1[t] = gelu_f(a);
    }
    __syncthreads();
    float a = b2[t];
    for (int i = 0; i < HID; i++) a += h1[i] * W2[i*DD + t];
    MODp[(size_t)b*DD + t] = a;
}

// ---------------- deltas: one wave per (n,b) row ----------------
__global__ __launch_bounds__(256) void deltas_kernel(
    const bf16* __restrict__ HE, const float* __restrict__ W2,
    const float* __restrict__ b2, float* __restrict__ out)
{
    int rid = blockIdx.x * 4 + (threadIdx.x >> 6);
    int lane = threadIdx.x & 63;
    int n = rid >> 6;
    int b = rid & 63;
    const bf16* hrow = HE + ((size_t)n * BB + b) * DD + lane * 8;
    const float* wrow = W2 + (size_t)n * DD + lane * 8;
    F4B8 hv; hv.f = *(const float4*)hrow;
    alignas(16) float wv[8];
    *(float4*)&wv[0] = *(const float4*)&wrow[0];
    *(float4*)&wv[4] = *(const float4*)&wrow[4];
    float s = 0.f;
#pragma unroll
    for (int j = 0; j < 8; j++) s += b2f(hv.h[j]) * wv[j];
#pragma unroll
    for (int m = 1; m < 64; m <<= 1) s += __shfl_xor(s, m, 64);
    if (lane == 0) out[b * NN + n] = s + b2[n];
}

// ---------------- host-side GEMM dispatch helper ----------------
template<int BM,int BN,int WM,int WN,int ACT,bool HB,typename TC>
static inline void launch2(bool useT, dim3 grid, hipStream_t s,
    const bf16* A, const float* Wf, const bf16* Wt, const float* bias, TC* C,
    int K, int lda, int ldbF, int ldbT, int ldc,
    long long sAg, long long sBg, long long sbg, long long sCg)
{
    if (useT)
        gemm2<BM,BN,WM,WN,ACT,true ,HB,false,false,bf16 ,TC><<<grid,WM*WN*64,0,s>>>(
            A, Wt, bias, C, K, lda, ldbT, ldc, sAg,sBg,sbg,sCg,
            nullptr, nullptr, nullptr);
    else
        gemm2<BM,BN,WM,WN,ACT,false,HB,false,false,float,TC><<<grid,WM*WN*64,0,s>>>(
            A, Wf, bias, C, K, lda, ldbF, ldc, sAg,sBg,sbg,sCg,
            nullptr, nullptr, nullptr);
}

// =========================== host side ===========================
extern "C" void kernel_launch(void* const* d_in, const int* in_sizes, int n_in,
                              void* d_out, int out_size, void* d_ws, size_t ws_size,
                              hipStream_t stream)
{
    const float* base_s = (const float*)d_in[0];
    const float* int_s  = (const float*)d_in[1];
    const float* targ   = (const float*)d_in[2];
    const float* maskv  = (const float*)d_in[3];
    const int*   nidx   = (const int*)  d_in[4];
    const float* gnoise = (const float*)d_in[5];
    const float* encW = (const float*)d_in[6];
    const float* encB = (const float*)d_in[7];
    const float* Wq = (const float*)d_in[8];  const float* bq = (const float*)d_in[9];
    const float* Wk = (const float*)d_in[10]; const float* bk = (const float*)d_in[11];
    const float* Wv = (const float*)d_in[12]; const float* bv = (const float*)d_in[13];
    const float* Wo = (const float*)d_in[14]; const float* bo = (const float*)d_in[15];
    const float* ln1g = (const float*)d_in[16]; const float* ln1b = (const float*)d_in[17];
    const float* Wff1 = (const float*)d_in[18]; const float* bff1 = (const float*)d_in[19];
    const float* Wff2 = (const float*)d_in[20]; const float* bff2 = (const float*)d_in[21];
    const float* ln2g = (const float*)d_in[22]; const float* ln2b = (const float*)d_in[23];
    const float* emb  = (const float*)d_in[24];
    const float* hW1 = (const float*)d_in[25]; const float* hb1 = (const float*)d_in[26];
    const float* hW2 = (const float*)d_in[27]; const float* hb2 = (const float*)d_in[28];
    const float* eW1 = (const float*)d_in[29]; const float* eb1 = (const float*)d_in[30];
    const float* eW2 = (const float*)d_in[31]; const float* eb2 = (const float*)d_in[32];
    const float* dpW = (const float*)d_in[33]; const float* dpB = (const float*)d_in[34];
    const float* dcW = (const float*)d_in[35]; const float* dcB = (const float*)d_in[36];

    float* out_deltas = (float*)d_out;
    float* out_logits = out_deltas + (size_t)BB*NN;
    float* out_adj    = out_logits + (size_t)BB*NN*NN;

    const size_t SZ = (size_t)NTOK * DD;     // 4,194,304 elements

    const size_t WT_ELEMS = (size_t)3*LL*DD*DD + (size_t)LL*DD*DD
                          + 2*(size_t)LL*DD*DFF + 2*(size_t)DD*DD;  // 13,107,200
    const size_t NEED_BIG = 6*SZ*2 + (size_t)BB*DD*4;
    const size_t NEED_P0  = NEED_BIG + WT_ELEMS*2 + (LL*LDQKV + 1024)*4;
    const bool big = ws_size >= NEED_BIG;
    const bool p0  = ws_size >= NEED_P0;

    bf16* X  = (bf16*)d_ws;
    bf16* PK = X + SZ;                 // packed QKV / Hid / DAG / scratch
    bf16* F2 = PK + 4*SZ;              // big only
    float* MODp = big ? (float*)(F2 + SZ) : (float*)(PK + 3*SZ);

    bf16 *wqkvT=nullptr,*woT=nullptr,*wf1T=nullptr,*wf2T=nullptr,*dagT=nullptr;
    float *qkvB=nullptr,*dagB=nullptr;
    if (p0) {
        bf16* WT = (bf16*)(MODp + (size_t)BB*DD);
        wqkvT = WT;                                 // [L][1536][512]
        woT   = wqkvT + (size_t)3*LL*DD*DD;         // [L][512][512]
        wf1T  = woT + (size_t)LL*DD*DD;             // [L][2048][512]
        wf2T  = wf1T + (size_t)LL*DD*DFF;           // [L][512][2048]
        dagT  = wf2T + (size_t)LL*DD*DFF;           // [1024][512]
        qkvB  = (float*)(dagT + 2*(size_t)DD*DD);
        dagB  = qkvB + LL*LDQKV;

        TXJobs J;
        int acc = 0;
        auto addjob = [&](int j, const float* in, bf16* out, int K, int N,
                          long long sIn, long long sOut, int G) {
            J.in[j]=in; J.out[j]=out; J.K[j]=K; J.N[j]=N; J.sIn[j]=sIn; J.sOut[j]=sOut;
            acc += G * (K>>5) * (N>>5); J.tileEnd[j]=acc;
        };
        addjob(0, Wq,  wqkvT,          DD, DD, (long long)DD*DD, (long long)LDQKV*DD, LL);
        addjob(1, Wk,  wqkvT+512*512,  DD, DD, (long long)DD*DD, (long long)LDQKV*DD, LL);
        addjob(2, Wv,  wqkvT+1024*512, DD, DD, (long long)DD*DD, (long long)LDQKV*DD, LL);
        addjob(3, Wo,  woT,            DD, DD, (long long)DD*DD, (long long)DD*DD,    LL);
        addjob(4, Wff1,wf1T,           DD, DFF,(long long)DD*DFF,(long long)DD*DFF,   LL);
        addjob(5, Wff2,wf2T,           DFF,DD, (long long)DD*DFF,(long long)DD*DFF,   LL);
        addjob(6, dpW, dagT,           DD, DD, 0, 0, 1);
        addjob(7, dcW, dagT+512*512,   DD, DD, 0, 0, 1);
        transpose_all<<<acc, 256, 0, stream>>>(J);
        pack_bias<<<(LL*LDQKV + 1024 + 255)/256, 256, 0, stream>>>(
            bq, bk, bv, dpB, dcB, qkvB, dagB);
    }

    encoder_kernel<<<NTOK*DD/8/256, 256, 0, stream>>>(
        base_s, int_s, targ, maskv, encW, encB, X);

    for (int l = 0; l < LL; ++l) {
        const size_t od = (size_t)l*DD*DD, of1 = (size_t)l*DD*DFF;
        // QKV -> packed PK [8192][1536]
        if (p0) {
            gemm2<128,128,2,4,0,true,true,false,false,bf16,bf16><<<dim3(12,64,1),512,0,stream>>>(
                X, wqkvT + (size_t)l*LDQKV*DD, qkvB + (size_t)l*LDQKV, PK,
                DD, DD, DD, LDQKV, 0,0,0,0, nullptr, nullptr, nullptr);
        } else {
            gemm2<128,128,2,4,0,false,true,false,false,float,bf16><<<dim3(4,64,1),512,0,stream>>>(
                X, Wq+od, bq+(size_t)l*DD, PK,        DD, DD, DD, LDQKV, 0,0,0,0,
                nullptr, nullptr, nullptr);
            gemm2<128,128,2,4,0,false,true,false,false,float,bf16><<<dim3(4,64,1),512,0,stream>>>(
                X, Wk+od, bk+(size_t)l*DD, PK+512,    DD, DD, DD, LDQKV, 0,0,0,0,
                nullptr, nullptr, nullptr);
            gemm2<128,128,2,4,0,false,true,false,false,float,bf16><<<dim3(4,64,1),512,0,stream>>>(
                X, Wv+od, bv+(size_t)l*DD, PK+1024,   DD, DD, DD, LDQKV, 0,0,0,0,
                nullptr, nullptr, nullptr);
        }
        attn_mfma<<<BB*HH, 256, 0, stream>>>(PK);   // O in place over Q slice
        launch2<128,128,2,4,0,true,bf16>(p0, dim3(4,64,1), stream,
            PK, Wo+od, woT+od, bo+(size_t)l*DD, PK+512, DD, LDQKV, DD, DD, LDQKV, 0,0,0,0);
        add_ln_kernel<<<NTOK/4, 256, 0, stream>>>(X, PK+512, LDQKV,
            ln1g+(size_t)l*DD, ln1b+(size_t)l*DD);

        if (big) {
            launch2<128,128,2,4,1,true,bf16>(p0, dim3(16,64,1), stream,
                X, Wff1+of1, wf1T+of1, bff1+(size_t)l*DFF, PK,
                DD, DD, DFF, DD, DFF, 0,0,0,0);
            launch2<128,128,2,4,0,true,bf16>(p0, dim3(4,64,1), stream,
                PK, Wff2+of1, wf2T+of1, bff2+(size_t)l*DD, F2,
                DFF, DFF, DD, DFF, DD, 0,0,0,0);
            add_ln_kernel<<<NTOK/4, 256, 0, stream>>>(X, F2, DD,
                ln2g+(size_t)l*DD, ln2b+(size_t)l*DD);
        } else {
            for (int c = 0; c < 4; ++c) {
                launch2<128,128,2,4,1,true,bf16>(p0, dim3(16,16,1), stream,
                    X + (size_t)c*2048*DD, Wff1+of1, wf1T+of1, bff1+(size_t)l*DFF, PK,
                    DD, DD, DFF, DD, DFF, 0,0,0,0);
                launch2<128,128,2,4,0,true,bf16>(p0, dim3(4,16,1), stream,
                    PK, Wff2+of1, wf2T+of1, bff2+(size_t)l*DD, PK + 2*SZ + (size_t)c*2048*DD,
                    DFF, DFF, DD, DFF, DD, 0,0,0,0);
            }
            add_ln_kernel<<<NTOK/4, 256, 0, stream>>>(X, PK + 2*SZ, DD,
                ln2g+(size_t)l*DD, ln2b+(size_t)l*DD);
        }
    }

    hyper_kernel<<<BB, 512, 0, stream>>>(nidx, emb, hW1, hb1, hW2, hb2, MODp);

    // per-node experts: grouped 64x512x512, f32-B path, fused xm (ASCALE)
    bf16* HEb = PK;
    gemm2<64,128,2,2,1,false,true,true,false,float,bf16><<<dim3(4,1,NN),256,0,stream>>>(
        X, eW1, eb1, HEb, DD, NN*DD, DD, DD,
        DD, (long long)DD*DD, DD, (long long)BB*DD, MODp, nullptr, nullptr);
    deltas_kernel<<<NN*BB/4, 256, 0, stream>>>(HEb, eW2, eb2, out_deltas);

    // DAG heads -> packed [8192][1024] in PK (after deltas consumed HE)
    bf16* DAGb = PK;
    if (p0) {
        gemm2<128,128,2,4,0,true,true,false,false,bf16,bf16><<<dim3(8,64,1),512,0,stream>>>(
            X, dagT, dagB, DAGb, DD, DD, DD, 1024, 0,0,0,0, nullptr, nullptr, nullptr);
    } else {
        gemm2<128,128,2,4,0,false,true,false,false,float,bf16><<<dim3(4,64,1),512,0,stream>>>(
            X, dpW, dpB, DAGb,       DD, DD, DD, 1024, 0,0,0,0, nullptr, nullptr, nullptr);
        gemm2<128,128,2,4,0,false,true,false,false,float,bf16><<<dim3(4,64,1),512,0,stream>>>(
            X, dcW, dcB, DAGb + 512, DD, DD, DD, 1024, 0,0,0,0, nullptr, nullptr, nullptr);
    }
    // logits[b] = P[b] @ C[b]^T, f32 into d_out; adj fused in epilogue
    gemm2<64,64,2,2,0,true,false,false,true,bf16,float><<<dim3(2,2,BB),256,0,stream>>>(
        DAGb, DAGb + 512, (const float*)nullptr, out_logits,
        DD, 1024, 1024, NN,
        (long long)NN*1024, (long long)NN*1024, 0, (long long)NN*NN,
        nullptr, gnoise, out_adj);

    (void)in_sizes; (void)n_in; (void)out_size;
}

// Round 12
// 565.127 us; speedup vs baseline: 1.0553x; 1.0553x over previous
//
#include <hip/hip_runtime.h>
#include <hip/hip_bf16.h>
#include <math.h>

// ---- problem constants ----
#define BB 64
#define NN 128
#define DD 512
#define DFF 2048
#define HH 8
#define DHH 64
#define EE 32
#define HID 64
#define LL 4
#define NTOK (BB*NN)          // 8192
#define LDQKV 1536

typedef __hip_bfloat16 bf16;
typedef __attribute__((ext_vector_type(8))) short short8v;   // 8 bf16 (4 VGPRs)
typedef __attribute__((ext_vector_type(4))) float f32x4v;    // 4 f32 acc

__device__ __forceinline__ float b2f(bf16 x) { return __bfloat162float(x); }
__device__ __forceinline__ bf16 f2b(float x) { return __float2bfloat16(x); }
__device__ __forceinline__ float gelu_f(float x) {
    return 0.5f * x * (1.0f + erff(x * 0.7071067811865476f));
}
// async global->LDS, 16B/lane; LDS dest is wave-uniform base + lane*16
__device__ __forceinline__ void glds16(const bf16* g, bf16* l) {
    __builtin_amdgcn_global_load_lds(
        (const __attribute__((address_space(1))) unsigned int*)g,
        (__attribute__((address_space(3))) unsigned int*)l,
        16, 0, 0);
}

union F4B8 { float4 f; bf16 h[8]; };
union B2U { bf16 h[2]; unsigned int u; };

// ---------------- merged weight prep: 8 transpose jobs in one launch -------
#define NJOBS 8
struct TXJobs {
    const float* in[NJOBS];
    bf16* out[NJOBS];
    int K[NJOBS], N[NJOBS];
    long long sIn[NJOBS], sOut[NJOBS];
    int tileEnd[NJOBS];          // inclusive prefix sum of G*(K/32)*(N/32)
};
__global__ __launch_bounds__(256) void transpose_all(TXJobs jobs)
{
    __shared__ float t[32][33];
    int tile = blockIdx.x;
    int j = 0;
    while (j < NJOBS - 1 && tile >= jobs.tileEnd[j]) ++j;
    int base = j ? jobs.tileEnd[j-1] : 0;
    int local = tile - base;
    const int K = jobs.K[j], N = jobs.N[j];
    const int tpg = (K >> 5) * (N >> 5);
    int g  = local / tpg;
    int r  = local % tpg;
    int tX = r % (N >> 5), tY = r / (N >> 5);
    const float* in = jobs.in[j] + (size_t)g * jobs.sIn[j];
    bf16* out = jobs.out[j] + (size_t)g * jobs.sOut[j];
    int n0 = tX * 32, k0 = tY * 32;
    int tx = threadIdx.x & 31, ty = threadIdx.x >> 5;
#pragma unroll
    for (int i = 0; i < 32; i += 8)
        t[ty + i][tx] = in[(size_t)(k0 + ty + i) * N + n0 + tx];
    __syncthreads();
#pragma unroll
    for (int i = 0; i < 32; i += 8)
        out[(size_t)(n0 + ty + i) * K + k0 + tx] = f2b(t[tx][ty + i]);
}

// merged bias packing: qkvB [L][1536] then dagB [1024]
__global__ __launch_bounds__(256) void pack_bias(
    const float* __restrict__ bq, const float* __restrict__ bk,
    const float* __restrict__ bv, const float* __restrict__ dp,
    const float* __restrict__ dc, float* __restrict__ qkvB,
    float* __restrict__ dagB)
{
    int i = blockIdx.x * 256 + threadIdx.x;
    if (i < LL * LDQKV) {
        int l = i / LDQKV, j = i % LDQKV;
        float v = (j < 512) ? bq[l*512 + j]
                : (j < 1024 ? bk[l*512 + j - 512] : bv[l*512 + j - 1024]);
        qkvB[i] = v;
    } else if (i < LL * LDQKV + 1024) {
        int j = i - LL * LDQKV;
        dagB[j] = (j < 512) ? dp[j] : dc[j - 512];
    }
}

// ---------------- encoder ----------------
__global__ __launch_bounds__(256) void encoder_kernel(
    const float* __restrict__ bs, const float* __restrict__ ins,
    const float* __restrict__ tr, const float* __restrict__ im,
    const float* __restrict__ encW, const float* __restrict__ encB,
    bf16* __restrict__ X)
{
    int idx = blockIdx.x * 256 + threadIdx.x;
    size_t i8 = (size_t)idx * 8;
    int d0 = (int)(i8 & (DD - 1));
    int t  = (int)(i8 >> 9);
    float f0 = bs[t], f1 = ins[t], f2 = tr[t], f3 = im[t];
    alignas(16) float acc[8], w[8];
    *(float4*)&acc[0] = *(const float4*)&encB[d0];
    *(float4*)&acc[4] = *(const float4*)&encB[d0 + 4];
    const float fs[4] = {f0, f1, f2, f3};
#pragma unroll
    for (int k = 0; k < 4; k++) {
        *(float4*)&w[0] = *(const float4*)&encW[k * DD + d0];
        *(float4*)&w[4] = *(const float4*)&encW[k * DD + d0 + 4];
#pragma unroll
        for (int j = 0; j < 8; j++) acc[j] = fmaf(fs[k], w[j], acc[j]);
    }
    F4B8 o;
#pragma unroll
    for (int j = 0; j < 8; j++) o.h[j] = f2b(acc[j]);
    *(float4*)&X[i8] = o.f;
}

// ---------------- MFMA GEMM ----------------
// TRANSB (bf16 [N][K]): m97 structure — global_load_lds staging, pre-swizzled
// source, linear LDS, 2-buffer, 1 barrier / K-step (round-10 proven form).
// !TRANSB (f32 [K][N]): reg-staged dbuf with transpose+cvt (expert GEMM);
//   ASCALE multiplies A by modp[row*DD + k] during commit (fused xm).
// FUSE_ADJ: epilogue also writes adj = sigmoid(C + gn) (logits GEMM).
template<int BM,int BN,int WM,int WN,int ACT,bool TRANSB,bool HAS_BIAS,
         bool ASCALE,bool FUSE_ADJ,typename TB,typename TC>
__global__ __launch_bounds__(WM*WN*64) void gemm2(
    const bf16* __restrict__ A, const TB* __restrict__ Bw,
    const float* __restrict__ bias, TC* __restrict__ C,
    int K, int lda, int ldb, int ldc,
    long long sAg, long long sBg, long long sbg, long long sCg,
    const float* __restrict__ modp, const float* __restrict__ gn,
    float* __restrict__ adjout)
{
    constexpr int BK = 64;
    constexpr int NT = WM*WN*64;
    constexpr int NW = NT/64;
    constexpr int MI = BM/WM/16;
    constexpr int NI = BN/WN/16;
    constexpr int LDK = TRANSB ? BK : (BK + 8);
    constexpr int LDC = BN + 8;
    constexpr size_t SH_AB = (size_t)2*(BM+BN)*LDK*sizeof(bf16);
    constexpr size_t SH_C  = (size_t)BM*LDC*sizeof(TC);
    __shared__ __align__(16) char smem[(SH_AB > SH_C ? SH_AB : SH_C)];
    bf16* AsB = (bf16*)smem;                 // [2][BM][LDK]
    bf16* BsB = AsB + (size_t)2*BM*LDK;      // [2][BN][LDK]
    TC*   Cs  = (TC*)smem;                   // [BM][LDC]

    const int g = blockIdx.z;
    const bf16* Ag = A + (size_t)g * sAg;
    const TB*   Bg = Bw + (size_t)g * sBg;

    // XCD-chunked swizzle (bijective when nwg % 8 == 0; skip grouped)
    int bx = blockIdx.x, by = blockIdx.y;
    if (gridDim.z == 1) {
        int nwg = gridDim.x * gridDim.y;
        if ((nwg & 7) == 0) {
            int id = by * gridDim.x + bx;
            id = (id & 7) * (nwg >> 3) + (id >> 3);
            bx = id % gridDim.x;
            by = id / gridDim.x;
        }
    }
    const int m0 = by * BM, n0 = bx * BN;
    const int tid = threadIdx.x, lane = tid & 63, wid = tid >> 6;
    const int wm = wid / WN, wn = wid % WN;
    const int lr = lane & 15, lq = lane >> 4;
    const int KT = K / BK;

    f32x4v acc[MI][NI];
#pragma unroll
    for (int mi = 0; mi < MI; mi++)
#pragma unroll
        for (int ni = 0; ni < NI; ni++)
            acc[mi][ni] = (f32x4v){0.f, 0.f, 0.f, 0.f};

    if constexpr (TRANSB) {
        // ---- m97-style: glds direct staging, pre-swizzled source ----
        auto stage = [&](int kt, int p) {
#pragma unroll
            for (int q = wid; q < BM/8; q += NW) {
                int r = q*8 + (lane >> 3), sp = lane & 7;
                glds16(Ag + (size_t)(m0 + r)*lda + kt*BK + ((sp ^ (r & 7)) << 3),
                       AsB + ((size_t)p*BM + q*8)*BK);
            }
#pragma unroll
            for (int q = wid; q < BN/8; q += NW) {
                int r = q*8 + (lane >> 3), sp = lane & 7;
                glds16((const bf16*)Bg + (size_t)(n0 + r)*ldb + kt*BK + ((sp ^ (r & 7)) << 3),
                       BsB + ((size_t)p*BN + q*8)*BK);
            }
        };
        stage(0, 0);
        __syncthreads();
        const int rx7 = lr & 7;
        int p = 0;
        for (int kt = 0; kt < KT; ++kt) {
            if (kt + 1 < KT) stage(kt + 1, p ^ 1);   // in flight during MFMA
#pragma unroll
            for (int kk = 0; kk < 2; ++kk) {
                const int colo = ((((kk << 2) | lq) ^ rx7) << 3);
                short8v av[MI], bv[NI];
#pragma unroll
                for (int mi = 0; mi < MI; ++mi) {
                    int row = wm*(BM/WM) + mi*16 + lr;
                    av[mi] = *(const short8v*)&AsB[((size_t)p*BM + row)*BK + colo];
                }
#pragma unroll
                for (int ni = 0; ni < NI; ++ni) {
                    int row = wn*(BN/WN) + ni*16 + lr;
                    bv[ni] = *(const short8v*)&BsB[((size_t)p*BN + row)*BK + colo];
                }
#pragma unroll
                for (int mi = 0; mi < MI; ++mi)
#pragma unroll
                    for (int ni = 0; ni < NI; ++ni)
                        acc[mi][ni] = __builtin_amdgcn_mfma_f32_16x16x32_bf16(
                            av[mi], bv[ni], acc[mi][ni], 0, 0, 0);
            }
            __syncthreads();   // drains glds (vmcnt) + frag reads; swap buffers
            p ^= 1;
        }
    } else {
        // ---- f32-B path: reg-staged dbuf with transpose+cvt ----
        constexpr int RA  = (BM*(BK/8))/NT;
        constexpr int RBF = (BK*(BN/4))/NT;
        float4 rA[RA];
        float4 rF[RBF];
        int staged_kt = 0;
        auto issue = [&](int kt) {
            staged_kt = kt;
#pragma unroll
            for (int r = 0; r < RA; ++r) {
                int c = tid + r*NT; int row = c >> 3, k8 = (c & 7) << 3;
                rA[r] = *(const float4*)(Ag + (size_t)(m0+row)*lda + kt*BK + k8);
            }
#pragma unroll
            for (int r = 0; r < RBF; ++r) {
                int c = tid + r*NT; int kk = c/(BN/4), n4 = (c%(BN/4))*4;
                rF[r] = *(const float4*)((const float*)Bg + (size_t)(kt*BK+kk)*ldb + n0 + n4);
            }
        };
        auto commit = [&](int p) {
#pragma unroll
            for (int r = 0; r < RA; ++r) {
                int c = tid + r*NT; int row = c >> 3, k8 = (c & 7) << 3;
                if constexpr (ASCALE) {
                    F4B8 u; u.f = rA[r];
                    alignas(16) float m8[8];
                    const float* mp = modp + (size_t)(m0+row)*DD + staged_kt*BK + k8;
                    *(float4*)&m8[0] = *(const float4*)mp;
                    *(float4*)&m8[4] = *(const float4*)(mp + 4);
#pragma unroll
                    for (int jj = 0; jj < 8; ++jj)
                        u.h[jj] = f2b(b2f(u.h[jj]) * m8[jj]);
                    *(float4*)&AsB[((size_t)p*BM + row)*LDK + k8] = u.f;
                } else {
                    *(float4*)&AsB[((size_t)p*BM + row)*LDK + k8] = rA[r];
                }
            }
#pragma unroll
            for (int r = 0; r < RBF; ++r) {
                int c = tid + r*NT; int kk = c/(BN/4), n4 = (c%(BN/4))*4;
                int kg = kk >> 3, kw = kk & 7;
                alignas(16) float vv[4]; *(float4*)vv = rF[r];
#pragma unroll
                for (int i = 0; i < 4; ++i) {
                    int n = n4 + i;
                    BsB[((size_t)p*BN + n)*LDK + (((kg ^ ((n>>2)&7)) << 3) | kw)] = f2b(vv[i]);
                }
            }
        };
        issue(0); commit(0); __syncthreads();
        for (int kt = 0; kt < KT; ++kt) {
            if (kt + 1 < KT) issue(kt + 1);
            const int p = kt & 1;
#pragma unroll
            for (int kk = 0; kk < 2; ++kk) {
                short8v av[MI], bv[NI];
#pragma unroll
                for (int mi = 0; mi < MI; ++mi) {
                    int row = wm*(BM/WM) + mi*16 + lr;
                    av[mi] = *(const short8v*)&AsB[((size_t)p*BM + row)*LDK + kk*32 + lq*8];
                }
#pragma unroll
                for (int ni = 0; ni < NI; ++ni) {
                    int row = wn*(BN/WN) + ni*16 + lr;
                    int col = (((kk*4 + lq) ^ ((row>>2)&7)) << 3);
                    bv[ni] = *(const short8v*)&BsB[((size_t)p*BN + row)*LDK + col];
                }
#pragma unroll
                for (int mi = 0; mi < MI; ++mi)
#pragma unroll
                    for (int ni = 0; ni < NI; ++ni)
                        acc[mi][ni] = __builtin_amdgcn_mfma_f32_16x16x32_bf16(
                            av[mi], bv[ni], acc[mi][ni], 0, 0, 0);
            }
            if (kt + 1 < KT) { commit((kt + 1) & 1); }
            __syncthreads();
        }
    }
    __syncthreads();     // safe to reuse smem as C tile

    // stage C (bias + act) into LDS
#pragma unroll
    for (int mi = 0; mi < MI; ++mi) {
        int rb = wm*(BM/WM) + mi*16 + lq*4;
#pragma unroll
        for (int ni = 0; ni < NI; ++ni) {
            int cc = wn*(BN/WN) + ni*16 + lr;
            float bvv = 0.f;
            if constexpr (HAS_BIAS) bvv = bias[(size_t)g*sbg + n0 + cc];
#pragma unroll
            for (int r = 0; r < 4; ++r) {
                float v = acc[mi][ni][r] + bvv;
                if (ACT == 1) v = gelu_f(v);
                if constexpr (sizeof(TC) == 2) Cs[(rb+r)*LDC + cc] = (TC)f2b(v);
                else ((float*)Cs)[(rb+r)*LDC + cc] = v;
            }
        }
    }
    __syncthreads();

    // coalesced vector store: 16B per lane (+ optional fused adj)
    constexpr int VEC = 16 / sizeof(TC);
#pragma unroll
    for (int c = tid; c < BM*(BN/VEC); c += NT) {
        int row = c / (BN/VEC), col = (c % (BN/VEC)) * VEC;
        size_t gidx = (size_t)g*sCg + (size_t)(m0+row)*ldc + n0 + col;
        *(float4*)&C[gidx] = *(const float4*)&Cs[row*LDC + col];
        if constexpr (FUSE_ADJ) {
            float4 cv = *(const float4*)&Cs[row*LDC + col];
            float4 g4 = *(const float4*)&gn[gidx];
            float4 a4;
            a4.x = 1.0f / (1.0f + __expf(-(cv.x + g4.x)));
            a4.y = 1.0f / (1.0f + __expf(-(cv.y + g4.y)));
            a4.z = 1.0f / (1.0f + __expf(-(cv.z + g4.z)));
            a4.w = 1.0f / (1.0f + __expf(-(cv.w + g4.w)));
            *(float4*)&adjout[gidx] = a4;
        }
    }
}

// ---------------- MFMA fused attention on packed QKV [8192][1536] ----------
__global__ __launch_bounds__(256) void attn_mfma(bf16* __restrict__ QKV)
{
    __shared__ bf16 Ps[NN][NN + 8];
    __shared__ bf16 Vt[DHH][NN + 8];
    int bh = blockIdx.x;
    int h = bh & (HH - 1);
    int b = bh >> 3;
    const int tid = threadIdx.x;
    const int lane = tid & 63;
    const int w = tid >> 6;
    const int lr = lane & 15;
    const int lq = lane >> 4;
    const size_t baseQ = (size_t)(b * NN) * LDQKV + h * DHH;
    const size_t baseK = baseQ + 512;
    const size_t baseV = baseQ + 1024;

    for (int c = tid; c < 512; c += 256) {
        int m = (c >> 3) * 2;
        int d8 = (c & 7) * 8;
        F4B8 v0, v1;
        v0.f = *(const float4*)(QKV + baseV + (size_t)m * LDQKV + d8);
        v1.f = *(const float4*)(QKV + baseV + (size_t)(m + 1) * LDQKV + d8);
#pragma unroll
        for (int j = 0; j < 8; j++) {
            B2U pk; pk.h[0] = v0.h[j]; pk.h[1] = v1.h[j];
            *(unsigned int*)&Vt[d8 + j][m] = pk.u;
        }
    }

    f32x4v sacc[2][8];
#pragma unroll
    for (int mi = 0; mi < 2; mi++)
#pragma unroll
        for (int ni = 0; ni < 8; ni++)
            sacc[mi][ni] = (f32x4v){0.f, 0.f, 0.f, 0.f};
#pragma unroll
    for (int ks = 0; ks < 2; ks++) {
        short8v aq[2];
#pragma unroll
        for (int mi = 0; mi < 2; mi++) {
            int row = w * 32 + mi * 16 + lr;
            aq[mi] = *(const short8v*)(QKV + baseQ + (size_t)row * LDQKV + ks * 32 + lq * 8);
        }
#pragma unroll
        for (int ni = 0; ni < 8; ni++) {
            int col = ni * 16 + lr;
            short8v bk = *(const short8v*)(QKV + baseK + (size_t)col * LDQKV + ks * 32 + lq * 8);
#pragma unroll
            for (int mi = 0; mi < 2; mi++)
                sacc[mi][ni] = __builtin_amdgcn_mfma_f32_16x16x32_bf16(
                    aq[mi], bk, sacc[mi][ni], 0, 0, 0);
        }
    }

#pragma unroll
    for (int mi = 0; mi < 2; mi++) {
#pragma unroll
        for (int r = 0; r < 4; r++) {
            float mx = -1e30f;
#pragma unroll
            for (int ni = 0; ni < 8; ni++)
                mx = fmaxf(mx, sacc[mi][ni][r]);
            mx = fmaxf(mx, __shfl_xor(mx, 1, 64));
            mx = fmaxf(mx, __shfl_xor(mx, 2, 64));
            mx = fmaxf(mx, __shfl_xor(mx, 4, 64));
            mx = fmaxf(mx, __shfl_xor(mx, 8, 64));
            mx *= 0.125f;
            float s = 0.f;
#pragma unroll
            for (int ni = 0; ni < 8; ni++) {
                float e = __expf(sacc[mi][ni][r] * 0.125f - mx);
                sacc[mi][ni][r] = e; s += e;
            }
            s += __shfl_xor(s, 1, 64);
            s += __shfl_xor(s, 2, 64);
            s += __shfl_xor(s, 4, 64);
            s += __shfl_xor(s, 8, 64);
            float inv = 1.0f / s;
            int row = w * 32 + mi * 16 + lq * 4 + r;
#pragma unroll
            for (int ni = 0; ni < 8; ni++)
                Ps[row][ni * 16 + lr] = f2b(sacc[mi][ni][r] * inv);
        }
    }
    __syncthreads();

    f32x4v oacc[2][4];
#pragma unroll
    for (int mi = 0; mi < 2; mi++)
#pragma unroll
        for (int ni = 0; ni < 4; ni++)
            oacc[mi][ni] = (f32x4v){0.f, 0.f, 0.f, 0.f};
#pragma unroll
    for (int ks = 0; ks < 4; ks++) {
        short8v ap[2];
#pragma unroll
        for (int mi = 0; mi < 2; mi++)
            ap[mi] = *(const short8v*)&Ps[w * 32 + mi * 16 + lr][ks * 32 + lq * 8];
#pragma unroll
        for (int ni = 0; ni < 4; ni++) {
            short8v bv = *(const short8v*)&Vt[ni * 16 + lr][ks * 32 + lq * 8];
#pragma unroll
            for (int mi = 0; mi < 2; mi++)
                oacc[mi][ni] = __builtin_amdgcn_mfma_f32_16x16x32_bf16(
                    ap[mi], bv, oacc[mi][ni], 0, 0, 0);
        }
    }
    __syncthreads();           // Ps fragment reads done — reuse Ps as O tile
#pragma unroll
    for (int mi = 0; mi < 2; mi++)
#pragma unroll
        for (int ni = 0; ni < 4; ni++) {
            int d = ni * 16 + lr;
#pragma unroll
            for (int r = 0; r < 4; r++) {
                int row = w * 32 + mi * 16 + lq * 4 + r;
                Ps[row][d] = f2b(oacc[mi][ni][r]);
            }
        }
    __syncthreads();
    for (int c = tid; c < NN * (DHH/8); c += 256) {
        int row = c >> 3, d8 = (c & 7) * 8;
        *(float4*)(QKV + baseQ + (size_t)row * LDQKV + d8) = *(const float4*)&Ps[row][d8];
    }
}

// ---------------- add+LN: one wave per token; R has stride ldr ------------
__global__ __launch_bounds__(256) void add_ln_kernel(
    bf16* __restrict__ X, const bf16* __restrict__ R, int ldr,
    const float* __restrict__ g, const float* __restrict__ bt)
{
    int tok = blockIdx.x * 4 + (threadIdx.x >> 6);
    int lane = threadIdx.x & 63;
    size_t base = (size_t)tok * DD + lane * 8;
    size_t rbase = (size_t)tok * ldr + lane * 8;
    F4B8 x, r;
    x.f = *(const float4*)&X[base];
    r.f = *(const float4*)&R[rbase];
    float v[8]; float s = 0.f, s2 = 0.f;
#pragma unroll
    for (int j = 0; j < 8; j++) {
        v[j] = b2f(x.h[j]) + b2f(r.h[j]);
        s += v[j]; s2 += v[j] * v[j];
    }
#pragma unroll
    for (int m = 1; m < 64; m <<= 1) {
        s  += __shfl_xor(s, m, 64);
        s2 += __shfl_xor(s2, m, 64);
    }
    float mean = s * (1.0f / 512.0f);
    float var = fmaxf(s2 * (1.0f / 512.0f) - mean * mean, 0.0f);
    float rstd = rsqrtf(var + 1e-5f);
    alignas(16) float gv[8], bv[8];
    *(float4*)&gv[0] = *(const float4*)&g[lane * 8];
    *(float4*)&gv[4] = *(const float4*)&g[lane * 8 + 4];
    *(float4*)&bv[0] = *(const float4*)&bt[lane * 8];
    *(float4*)&bv[4] = *(const float4*)&bt[lane * 8 + 4];
    F4B8 o;
#pragma unroll
    for (int j = 0; j < 8; j++)
        o.h[j] = f2b((v[j] - mean) * rstd * gv[j] + bv[j]);
    *(float4*)&X[base] = o.f;
}

// ---------------- hyper-network ----------------
__global__ __launch_bounds__(512) void hyper_kernel(
    const int* __restrict__ idx, const float* __restrict__ emb,
    const float* __restrict__ W1, const float* __restrict__ b1,
    const float* __restrict__ W2, const float* __restrict__ b2,
    float* __restrict__ MODp)
{
    int b = blockIdx.x;
    int t = threadIdx.x;
    __shared__ float instr[EE];
    __shared__ float h1[HID];
    int id = idx[b];
    if (t < EE) instr[t] = emb[id*EE + t];
    __syncthreads();
    if (t < HID) {
        float a = b1[t];
        for (int i = 0; i < EE; i++) a += instr[i] * W1[i*HID + t];
        h1[t] = gelu_f(a);
    }
    __syncthreads();
    float a = b2[t];
    for (int i = 0; i < HID; i++) a += h1[i] * W2[i*DD + t];
    MODp[(size_t)b*DD + t] = a;
}

// ---------------- deltas: one wave per (n,b) row ----------------
__global__ __launch_bounds__(256) void deltas_kernel(
    const bf16* __restrict__ HE, const float* __restrict__ W2,
    const float* __restrict__ b2, float* __restrict__ out)
{
    int rid = blockIdx.x * 4 + (threadIdx.x >> 6);
    int lane = threadIdx.x & 63;
    int n = rid >> 6;
    int b = rid & 63;
    const bf16* hrow = HE + ((size_t)n * BB + b) * DD + lane * 8;
    const float* wrow = W2 + (size_t)n * DD + lane * 8;
    F4B8 hv; hv.f = *(const float4*)hrow;
    alignas(16) float wv[8];
    *(float4*)&wv[0] = *(const float4*)&wrow[0];
    *(float4*)&wv[4] = *(const float4*)&wrow[4];
    float s = 0.f;
#pragma unroll
    for (int j = 0; j < 8; j++) s += b2f(hv.h[j]) * wv[j];
#pragma unroll
    for (int m = 1; m < 64; m <<= 1) s += __shfl_xor(s, m, 64);
    if (lane == 0) out[b * NN + n] = s + b2[n];
}

// ---------------- host-side GEMM dispatch helper ----------------
template<int BM,int BN,int WM,int WN,int ACT,bool HB,typename TC>
static inline void launch2(bool useT, dim3 grid, hipStream_t s,
    const bf16* A, const float* Wf, const bf16* Wt, const float* bias, TC* C,
    int K, int lda, int ldbF, int ldbT, int ldc,
    long long sAg, long long sBg, long long sbg, long long sCg)
{
    if (useT)
        gemm2<BM,BN,WM,WN,ACT,true ,HB,false,false,bf16 ,TC><<<grid,WM*WN*64,0,s>>>(
            A, Wt, bias, C, K, lda, ldbT, ldc, sAg,sBg,sbg,sCg,
            nullptr, nullptr, nullptr);
    else
        gemm2<BM,BN,WM,WN,ACT,false,HB,false,false,float,TC><<<grid,WM*WN*64,0,s>>>(
            A, Wf, bias, C, K, lda, ldbF, ldc, sAg,sBg,sbg,sCg,
            nullptr, nullptr, nullptr);
}

// =========================== host side ===========================
extern "C" void kernel_launch(void* const* d_in, const int* in_sizes, int n_in,
                              void* d_out, int out_size, void* d_ws, size_t ws_size,
                              hipStream_t stream)
{
    const float* base_s = (const float*)d_in[0];
    const float* int_s  = (const float*)d_in[1];
    const float* targ   = (const float*)d_in[2];
    const float* maskv  = (const float*)d_in[3];
    const int*   nidx   = (const int*)  d_in[4];
    const float* gnoise = (const float*)d_in[5];
    const float* encW = (const float*)d_in[6];
    const float* encB = (const float*)d_in[7];
    const float* Wq = (const float*)d_in[8];  const float* bq = (const float*)d_in[9];
    const float* Wk = (const float*)d_in[10]; const float* bk = (const float*)d_in[11];
    const float* Wv = (const float*)d_in[12]; const float* bv = (const float*)d_in[13];
    const float* Wo = (const float*)d_in[14]; const float* bo = (const float*)d_in[15];
    const float* ln1g = (const float*)d_in[16]; const float* ln1b = (const float*)d_in[17];
    const float* Wff1 = (const float*)d_in[18]; const float* bff1 = (const float*)d_in[19];
    const float* Wff2 = (const float*)d_in[20]; const float* bff2 = (const float*)d_in[21];
    const float* ln2g = (const float*)d_in[22]; const float* ln2b = (const float*)d_in[23];
    const float* emb  = (const float*)d_in[24];
    const float* hW1 = (const float*)d_in[25]; const float* hb1 = (const float*)d_in[26];
    const float* hW2 = (const float*)d_in[27]; const float* hb2 = (const float*)d_in[28];
    const float* eW1 = (const float*)d_in[29]; const float* eb1 = (const float*)d_in[30];
    const float* eW2 = (const float*)d_in[31]; const float* eb2 = (const float*)d_in[32];
    const float* dpW = (const float*)d_in[33]; const float* dpB = (const float*)d_in[34];
    const float* dcW = (const float*)d_in[35]; const float* dcB = (const float*)d_in[36];

    float* out_deltas = (float*)d_out;
    float* out_logits = out_deltas + (size_t)BB*NN;
    float* out_adj    = out_logits + (size_t)BB*NN*NN;

    const size_t SZ = (size_t)NTOK * DD;     // 4,194,304 elements

    const size_t WT_ELEMS = (size_t)3*LL*DD*DD + (size_t)LL*DD*DD
                          + 2*(size_t)LL*DD*DFF + 2*(size_t)DD*DD;  // 13,107,200
    const size_t NEED_BIG = 6*SZ*2 + (size_t)BB*DD*4;
    const size_t NEED_P0  = NEED_BIG + WT_ELEMS*2 + (LL*LDQKV + 1024)*4;
    const bool big = ws_size >= NEED_BIG;
    const bool p0  = ws_size >= NEED_P0;

    bf16* X  = (bf16*)d_ws;
    bf16* PK = X + SZ;                 // packed QKV / Hid / DAG / scratch
    bf16* F2 = PK + 4*SZ;              // big only
    float* MODp = big ? (float*)(F2 + SZ) : (float*)(PK + 3*SZ);

    bf16 *wqkvT=nullptr,*woT=nullptr,*wf1T=nullptr,*wf2T=nullptr,*dagT=nullptr;
    float *qkvB=nullptr,*dagB=nullptr;
    if (p0) {
        bf16* WT = (bf16*)(MODp + (size_t)BB*DD);
        wqkvT = WT;                                 // [L][1536][512]
        woT   = wqkvT + (size_t)3*LL*DD*DD;         // [L][512][512]
        wf1T  = woT + (size_t)LL*DD*DD;             // [L][2048][512]
        wf2T  = wf1T + (size_t)LL*DD*DFF;           // [L][512][2048]
        dagT  = wf2T + (size_t)LL*DD*DFF;           // [1024][512]
        qkvB  = (float*)(dagT + 2*(size_t)DD*DD);
        dagB  = qkvB + LL*LDQKV;

        TXJobs J;
        int acc = 0;
        auto addjob = [&](int j, const float* in, bf16* out, int K, int N,
                          long long sIn, long long sOut, int G) {
            J.in[j]=in; J.out[j]=out; J.K[j]=K; J.N[j]=N; J.sIn[j]=sIn; J.sOut[j]=sOut;
            acc += G * (K>>5) * (N>>5); J.tileEnd[j]=acc;
        };
        addjob(0, Wq,  wqkvT,          DD, DD, (long long)DD*DD, (long long)LDQKV*DD, LL);
        addjob(1, Wk,  wqkvT+512*512,  DD, DD, (long long)DD*DD, (long long)LDQKV*DD, LL);
        addjob(2, Wv,  wqkvT+1024*512, DD, DD, (long long)DD*DD, (long long)LDQKV*DD, LL);
        addjob(3, Wo,  woT,            DD, DD, (long long)DD*DD, (long long)DD*DD,    LL);
        addjob(4, Wff1,wf1T,           DD, DFF,(long long)DD*DFF,(long long)DD*DFF,   LL);
        addjob(5, Wff2,wf2T,           DFF,DD, (long long)DD*DFF,(long long)DD*DFF,   LL);
        addjob(6, dpW, dagT,           DD, DD, 0, 0, 1);
        addjob(7, dcW, dagT+512*512,   DD, DD, 0, 0, 1);
        transpose_all<<<acc, 256, 0, stream>>>(J);
        pack_bias<<<(LL*LDQKV + 1024 + 255)/256, 256, 0, stream>>>(
            bq, bk, bv, dpB, dcB, qkvB, dagB);
    }

    encoder_kernel<<<NTOK*DD/8/256, 256, 0, stream>>>(
        base_s, int_s, targ, maskv, encW, encB, X);

    for (int l = 0; l < LL; ++l) {
        const size_t od = (size_t)l*DD*DD, of1 = (size_t)l*DD*DFF;
        // QKV -> packed PK [8192][1536]
        if (p0) {
            gemm2<128,128,2,4,0,true,true,false,false,bf16,bf16><<<dim3(12,64,1),512,0,stream>>>(
                X, wqkvT + (size_t)l*LDQKV*DD, qkvB + (size_t)l*LDQKV, PK,
                DD, DD, DD, LDQKV, 0,0,0,0, nullptr, nullptr, nullptr);
        } else {
            gemm2<128,128,2,4,0,false,true,false,false,float,bf16><<<dim3(4,64,1),512,0,stream>>>(
                X, Wq+od, bq+(size_t)l*DD, PK,        DD, DD, DD, LDQKV, 0,0,0,0,
                nullptr, nullptr, nullptr);
            gemm2<128,128,2,4,0,false,true,false,false,float,bf16><<<dim3(4,64,1),512,0,stream>>>(
                X, Wk+od, bk+(size_t)l*DD, PK+512,    DD, DD, DD, LDQKV, 0,0,0,0,
                nullptr, nullptr, nullptr);
            gemm2<128,128,2,4,0,false,true,false,false,float,bf16><<<dim3(4,64,1),512,0,stream>>>(
                X, Wv+od, bv+(size_t)l*DD, PK+1024,   DD, DD, DD, LDQKV, 0,0,0,0,
                nullptr, nullptr, nullptr);
        }
        attn_mfma<<<BB*HH, 256, 0, stream>>>(PK);   // O in place over Q slice
        // O-proj: BM=64 -> grid (4,128)=512 blocks (2 blocks/CU)
        launch2<64,128,2,4,0,true,bf16>(p0, dim3(4,128,1), stream,
            PK, Wo+od, woT+od, bo+(size_t)l*DD, PK+512, DD, LDQKV, DD, DD, LDQKV, 0,0,0,0);
        add_ln_kernel<<<NTOK/4, 256, 0, stream>>>(X, PK+512, LDQKV,
            ln1g+(size_t)l*DD, ln1b+(size_t)l*DD);

        if (big) {
            launch2<128,128,2,4,1,true,bf16>(p0, dim3(16,64,1), stream,
                X, Wff1+of1, wf1T+of1, bff1+(size_t)l*DFF, PK,
                DD, DD, DFF, DD, DFF, 0,0,0,0);
            // FFN2: BM=64 -> grid (4,128)=512 blocks (2 blocks/CU)
            launch2<64,128,2,4,0,true,bf16>(p0, dim3(4,128,1), stream,
                PK, Wff2+of1, wf2T+of1, bff2+(size_t)l*DD, F2,
                DFF, DFF, DD, DFF, DD, 0,0,0,0);
            add_ln_kernel<<<NTOK/4, 256, 0, stream>>>(X, F2, DD,
                ln2g+(size_t)l*DD, ln2b+(size_t)l*DD);
        } else {
            for (int c = 0; c < 4; ++c) {
                launch2<128,128,2,4,1,true,bf16>(p0, dim3(16,16,1), stream,
                    X + (size_t)c*2048*DD, Wff1+of1, wf1T+of1, bff1+(size_t)l*DFF, PK,
                    DD, DD, DFF, DD, DFF, 0,0,0,0);
                launch2<64,128,2,4,0,true,bf16>(p0, dim3(4,32,1), stream,
                    PK, Wff2+of1, wf2T+of1, bff2+(size_t)l*DD, PK + 2*SZ + (size_t)c*2048*DD,
                    DFF, DFF, DD, DFF, DD, 0,0,0,0);
            }
            add_ln_kernel<<<NTOK/4, 256, 0, stream>>>(X, PK + 2*SZ, DD,
                ln2g+(size_t)l*DD, ln2b+(size_t)l*DD);
        }
    }

    hyper_kernel<<<BB, 512, 0, stream>>>(nidx, emb, hW1, hb1, hW2, hb2, MODp);

    // per-node experts: grouped 64x512x512, f32-B path, fused xm (ASCALE)
    bf16* HEb = PK;
    gemm2<64,128,2,2,1,false,true,true,false,float,bf16><<<dim3(4,1,NN),256,0,stream>>>(
        X, eW1, eb1, HEb, DD, NN*DD, DD, DD,
        DD, (long long)DD*DD, DD, (long long)BB*DD, MODp, nullptr, nullptr);
    deltas_kernel<<<NN*BB/4, 256, 0, stream>>>(HEb, eW2, eb2, out_deltas);

    // DAG heads -> packed [8192][1024] in PK (after deltas consumed HE)
    bf16* DAGb = PK;
    if (p0) {
        gemm2<128,128,2,4,0,true,true,false,false,bf16,bf16><<<dim3(8,64,1),512,0,stream>>>(
            X, dagT, dagB, DAGb, DD, DD, DD, 1024, 0,0,0,0, nullptr, nullptr, nullptr);
    } else {
        gemm2<128,128,2,4,0,false,true,false,false,float,bf16><<<dim3(4,64,1),512,0,stream>>>(
            X, dpW, dpB, DAGb,       DD, DD, DD, 1024, 0,0,0,0, nullptr, nullptr, nullptr);
        gemm2<128,128,2,4,0,false,true,false,false,float,bf16><<<dim3(4,64,1),512,0,stream>>>(
            X, dcW, dcB, DAGb + 512, DD, DD, DD, 1024, 0,0,0,0, nullptr, nullptr, nullptr);
    }
    // logits[b] = P[b] @ C[b]^T, f32 into d_out; adj fused in epilogue
    gemm2<64,64,2,2,0,true,false,false,true,bf16,float><<<dim3(2,2,BB),256,0,stream>>>(
        DAGb, DAGb + 512, (const float*)nullptr, out_logits,
        DD, 1024, 1024, NN,
        (long long)NN*1024, (long long)NN*1024, 0, (long long)NN*NN,
        nullptr, gnoise, out_adj);

    (void)in_sizes; (void)n_in; (void)out_size;
}

// Round 13
// 547.999 us; speedup vs baseline: 1.0883x; 1.0313x over previous
//
#include <hip/hip_runtime.h>
#include <hip/hip_bf16.h>
#include <math.h>

// ---- problem constants ----
#define BB 64
#define NN 128
#define DD 512
#define DFF 2048
#define HH 8
#define DHH 64
#define EE 32
#define HID 64
#define LL 4
#define NTOK (BB*NN)          // 8192
#define LDQKV 1536

typedef __hip_bfloat16 bf16;
typedef __attribute__((ext_vector_type(8))) short short8v;   // 8 bf16 (4 VGPRs)
typedef __attribute__((ext_vector_type(4))) float f32x4v;    // 4 f32 acc

__device__ __forceinline__ float b2f(bf16 x) { return __bfloat162float(x); }
__device__ __forceinline__ bf16 f2b(float x) { return __float2bfloat16(x); }
__device__ __forceinline__ float gelu_f(float x) {
    return 0.5f * x * (1.0f + erff(x * 0.7071067811865476f));
}
// async global->LDS, 16B/lane; LDS dest is wave-uniform base + lane*16
__device__ __forceinline__ void glds16(const bf16* g, bf16* l) {
    __builtin_amdgcn_global_load_lds(
        (const __attribute__((address_space(1))) unsigned int*)g,
        (__attribute__((address_space(3))) unsigned int*)l,
        16, 0, 0);
}

union F4B8 { float4 f; bf16 h[8]; };
union B2U { bf16 h[2]; unsigned int u; };

// ---------------- merged weight prep: 8 transpose jobs in one launch -------
#define NJOBS 8
struct TXJobs {
    const float* in[NJOBS];
    bf16* out[NJOBS];
    int K[NJOBS], N[NJOBS];
    long long sIn[NJOBS], sOut[NJOBS];
    int tileEnd[NJOBS];          // inclusive prefix sum of G*(K/32)*(N/32)
};
__global__ __launch_bounds__(256) void transpose_all(TXJobs jobs)
{
    __shared__ float t[32][33];
    int tile = blockIdx.x;
    int j = 0;
    while (j < NJOBS - 1 && tile >= jobs.tileEnd[j]) ++j;
    int base = j ? jobs.tileEnd[j-1] : 0;
    int local = tile - base;
    const int K = jobs.K[j], N = jobs.N[j];
    const int tpg = (K >> 5) * (N >> 5);
    int g  = local / tpg;
    int r  = local % tpg;
    int tX = r % (N >> 5), tY = r / (N >> 5);
    const float* in = jobs.in[j] + (size_t)g * jobs.sIn[j];
    bf16* out = jobs.out[j] + (size_t)g * jobs.sOut[j];
    int n0 = tX * 32, k0 = tY * 32;
    int tx = threadIdx.x & 31, ty = threadIdx.x >> 5;
#pragma unroll
    for (int i = 0; i < 32; i += 8)
        t[ty + i][tx] = in[(size_t)(k0 + ty + i) * N + n0 + tx];
    __syncthreads();
#pragma unroll
    for (int i = 0; i < 32; i += 8)
        out[(size_t)(n0 + ty + i) * K + k0 + tx] = f2b(t[tx][ty + i]);
}

// merged bias packing: qkvB [L][1536] then dagB [1024]
__global__ __launch_bounds__(256) void pack_bias(
    const float* __restrict__ bq, const float* __restrict__ bk,
    const float* __restrict__ bv, const float* __restrict__ dp,
    const float* __restrict__ dc, float* __restrict__ qkvB,
    float* __restrict__ dagB)
{
    int i = blockIdx.x * 256 + threadIdx.x;
    if (i < LL * LDQKV) {
        int l = i / LDQKV, j = i % LDQKV;
        float v = (j < 512) ? bq[l*512 + j]
                : (j < 1024 ? bk[l*512 + j - 512] : bv[l*512 + j - 1024]);
        qkvB[i] = v;
    } else if (i < LL * LDQKV + 1024) {
        int j = i - LL * LDQKV;
        dagB[j] = (j < 512) ? dp[j] : dc[j - 512];
    }
}

// ---------------- encoder ----------------
__global__ __launch_bounds__(256) void encoder_kernel(
    const float* __restrict__ bs, const float* __restrict__ ins,
    const float* __restrict__ tr, const float* __restrict__ im,
    const float* __restrict__ encW, const float* __restrict__ encB,
    bf16* __restrict__ X)
{
    int idx = blockIdx.x * 256 + threadIdx.x;
    size_t i8 = (size_t)idx * 8;
    int d0 = (int)(i8 & (DD - 1));
    int t  = (int)(i8 >> 9);
    float f0 = bs[t], f1 = ins[t], f2 = tr[t], f3 = im[t];
    alignas(16) float acc[8], w[8];
    *(float4*)&acc[0] = *(const float4*)&encB[d0];
    *(float4*)&acc[4] = *(const float4*)&encB[d0 + 4];
    const float fs[4] = {f0, f1, f2, f3};
#pragma unroll
    for (int k = 0; k < 4; k++) {
        *(float4*)&w[0] = *(const float4*)&encW[k * DD + d0];
        *(float4*)&w[4] = *(const float4*)&encW[k * DD + d0 + 4];
#pragma unroll
        for (int j = 0; j < 8; j++) acc[j] = fmaf(fs[k], w[j], acc[j]);
    }
    F4B8 o;
#pragma unroll
    for (int j = 0; j < 8; j++) o.h[j] = f2b(acc[j]);
    *(float4*)&X[i8] = o.f;
}

// ---------------- MFMA GEMM ----------------
// TRANSB (bf16 [N][K]): m97 structure — global_load_lds staging, pre-swizzled
// source, linear LDS, 2-buffer, 1 barrier / K-step (round-10 proven form).
// !TRANSB (f32 [K][N]): reg-staged dbuf with transpose+cvt (expert GEMM);
//   ASCALE multiplies A by modp[row*DD + k] during commit (fused xm).
// FUSE_ADJ: epilogue also writes adj = sigmoid(C + gn) (logits GEMM).
template<int BM,int BN,int WM,int WN,int ACT,bool TRANSB,bool HAS_BIAS,
         bool ASCALE,bool FUSE_ADJ,typename TB,typename TC>
__global__ __launch_bounds__(WM*WN*64) void gemm2(
    const bf16* __restrict__ A, const TB* __restrict__ Bw,
    const float* __restrict__ bias, TC* __restrict__ C,
    int K, int lda, int ldb, int ldc,
    long long sAg, long long sBg, long long sbg, long long sCg,
    const float* __restrict__ modp, const float* __restrict__ gn,
    float* __restrict__ adjout)
{
    constexpr int BK = 64;
    constexpr int NT = WM*WN*64;
    constexpr int NW = NT/64;
    constexpr int MI = BM/WM/16;
    constexpr int NI = BN/WN/16;
    constexpr int LDK = TRANSB ? BK : (BK + 8);
    constexpr int LDC = BN + 8;
    constexpr size_t SH_AB = (size_t)2*(BM+BN)*LDK*sizeof(bf16);
    constexpr size_t SH_C  = (size_t)BM*LDC*sizeof(TC);
    __shared__ __align__(16) char smem[(SH_AB > SH_C ? SH_AB : SH_C)];
    bf16* AsB = (bf16*)smem;                 // [2][BM][LDK]
    bf16* BsB = AsB + (size_t)2*BM*LDK;      // [2][BN][LDK]
    TC*   Cs  = (TC*)smem;                   // [BM][LDC]

    const int g = blockIdx.z;
    const bf16* Ag = A + (size_t)g * sAg;
    const TB*   Bg = Bw + (size_t)g * sBg;

    // XCD-chunked swizzle (bijective when nwg % 8 == 0; skip grouped)
    int bx = blockIdx.x, by = blockIdx.y;
    if (gridDim.z == 1) {
        int nwg = gridDim.x * gridDim.y;
        if ((nwg & 7) == 0) {
            int id = by * gridDim.x + bx;
            id = (id & 7) * (nwg >> 3) + (id >> 3);
            bx = id % gridDim.x;
            by = id / gridDim.x;
        }
    }
    const int m0 = by * BM, n0 = bx * BN;
    const int tid = threadIdx.x, lane = tid & 63, wid = tid >> 6;
    const int wm = wid / WN, wn = wid % WN;
    const int lr = lane & 15, lq = lane >> 4;
    const int KT = K / BK;

    f32x4v acc[MI][NI];
#pragma unroll
    for (int mi = 0; mi < MI; mi++)
#pragma unroll
        for (int ni = 0; ni < NI; ni++)
            acc[mi][ni] = (f32x4v){0.f, 0.f, 0.f, 0.f};

    if constexpr (TRANSB) {
        // ---- m97-style: glds direct staging, pre-swizzled source ----
        auto stage = [&](int kt, int p) {
#pragma unroll
            for (int q = wid; q < BM/8; q += NW) {
                int r = q*8 + (lane >> 3), sp = lane & 7;
                glds16(Ag + (size_t)(m0 + r)*lda + kt*BK + ((sp ^ (r & 7)) << 3),
                       AsB + ((size_t)p*BM + q*8)*BK);
            }
#pragma unroll
            for (int q = wid; q < BN/8; q += NW) {
                int r = q*8 + (lane >> 3), sp = lane & 7;
                glds16((const bf16*)Bg + (size_t)(n0 + r)*ldb + kt*BK + ((sp ^ (r & 7)) << 3),
                       BsB + ((size_t)p*BN + q*8)*BK);
            }
        };
        stage(0, 0);
        __syncthreads();
        const int rx7 = lr & 7;
        int p = 0;
        for (int kt = 0; kt < KT; ++kt) {
            if (kt + 1 < KT) stage(kt + 1, p ^ 1);   // in flight during MFMA
#pragma unroll
            for (int kk = 0; kk < 2; ++kk) {
                const int colo = ((((kk << 2) | lq) ^ rx7) << 3);
                short8v av[MI], bv[NI];
#pragma unroll
                for (int mi = 0; mi < MI; ++mi) {
                    int row = wm*(BM/WM) + mi*16 + lr;
                    av[mi] = *(const short8v*)&AsB[((size_t)p*BM + row)*BK + colo];
                }
#pragma unroll
                for (int ni = 0; ni < NI; ++ni) {
                    int row = wn*(BN/WN) + ni*16 + lr;
                    bv[ni] = *(const short8v*)&BsB[((size_t)p*BN + row)*BK + colo];
                }
#pragma unroll
                for (int mi = 0; mi < MI; ++mi)
#pragma unroll
                    for (int ni = 0; ni < NI; ++ni)
                        acc[mi][ni] = __builtin_amdgcn_mfma_f32_16x16x32_bf16(
                            av[mi], bv[ni], acc[mi][ni], 0, 0, 0);
            }
            __syncthreads();   // drains glds (vmcnt) + frag reads; swap buffers
            p ^= 1;
        }
    } else {
        // ---- f32-B path: reg-staged dbuf with transpose+cvt ----
        constexpr int RA  = (BM*(BK/8))/NT;
        constexpr int RBF = (BK*(BN/4))/NT;
        float4 rA[RA];
        float4 rF[RBF];
        int staged_kt = 0;
        auto issue = [&](int kt) {
            staged_kt = kt;
#pragma unroll
            for (int r = 0; r < RA; ++r) {
                int c = tid + r*NT; int row = c >> 3, k8 = (c & 7) << 3;
                rA[r] = *(const float4*)(Ag + (size_t)(m0+row)*lda + kt*BK + k8);
            }
#pragma unroll
            for (int r = 0; r < RBF; ++r) {
                int c = tid + r*NT; int kk = c/(BN/4), n4 = (c%(BN/4))*4;
                rF[r] = *(const float4*)((const float*)Bg + (size_t)(kt*BK+kk)*ldb + n0 + n4);
            }
        };
        auto commit = [&](int p) {
#pragma unroll
            for (int r = 0; r < RA; ++r) {
                int c = tid + r*NT; int row = c >> 3, k8 = (c & 7) << 3;
                if constexpr (ASCALE) {
                    F4B8 u; u.f = rA[r];
                    alignas(16) float m8[8];
                    const float* mp = modp + (size_t)(m0+row)*DD + staged_kt*BK + k8;
                    *(float4*)&m8[0] = *(const float4*)mp;
                    *(float4*)&m8[4] = *(const float4*)(mp + 4);
#pragma unroll
                    for (int jj = 0; jj < 8; ++jj)
                        u.h[jj] = f2b(b2f(u.h[jj]) * m8[jj]);
                    *(float4*)&AsB[((size_t)p*BM + row)*LDK + k8] = u.f;
                } else {
                    *(float4*)&AsB[((size_t)p*BM + row)*LDK + k8] = rA[r];
                }
            }
#pragma unroll
            for (int r = 0; r < RBF; ++r) {
                int c = tid + r*NT; int kk = c/(BN/4), n4 = (c%(BN/4))*4;
                int kg = kk >> 3, kw = kk & 7;
                alignas(16) float vv[4]; *(float4*)vv = rF[r];
#pragma unroll
                for (int i = 0; i < 4; ++i) {
                    int n = n4 + i;
                    BsB[((size_t)p*BN + n)*LDK + (((kg ^ ((n>>2)&7)) << 3) | kw)] = f2b(vv[i]);
                }
            }
        };
        issue(0); commit(0); __syncthreads();
        for (int kt = 0; kt < KT; ++kt) {
            if (kt + 1 < KT) issue(kt + 1);
            const int p = kt & 1;
#pragma unroll
            for (int kk = 0; kk < 2; ++kk) {
                short8v av[MI], bv[NI];
#pragma unroll
                for (int mi = 0; mi < MI; ++mi) {
                    int row = wm*(BM/WM) + mi*16 + lr;
                    av[mi] = *(const short8v*)&AsB[((size_t)p*BM + row)*LDK + kk*32 + lq*8];
                }
#pragma unroll
                for (int ni = 0; ni < NI; ++ni) {
                    int row = wn*(BN/WN) + ni*16 + lr;
                    int col = (((kk*4 + lq) ^ ((row>>2)&7)) << 3);
                    bv[ni] = *(const short8v*)&BsB[((size_t)p*BN + row)*LDK + col];
                }
#pragma unroll
                for (int mi = 0; mi < MI; ++mi)
#pragma unroll
                    for (int ni = 0; ni < NI; ++ni)
                        acc[mi][ni] = __builtin_amdgcn_mfma_f32_16x16x32_bf16(
                            av[mi], bv[ni], acc[mi][ni], 0, 0, 0);
            }
            if (kt + 1 < KT) { commit((kt + 1) & 1); }
            __syncthreads();
        }
    }
    __syncthreads();     // safe to reuse smem as C tile

    // stage C (bias + act) into LDS
#pragma unroll
    for (int mi = 0; mi < MI; ++mi) {
        int rb = wm*(BM/WM) + mi*16 + lq*4;
#pragma unroll
        for (int ni = 0; ni < NI; ++ni) {
            int cc = wn*(BN/WN) + ni*16 + lr;
            float bvv = 0.f;
            if constexpr (HAS_BIAS) bvv = bias[(size_t)g*sbg + n0 + cc];
#pragma unroll
            for (int r = 0; r < 4; ++r) {
                float v = acc[mi][ni][r] + bvv;
                if (ACT == 1) v = gelu_f(v);
                if constexpr (sizeof(TC) == 2) Cs[(rb+r)*LDC + cc] = (TC)f2b(v);
                else ((float*)Cs)[(rb+r)*LDC + cc] = v;
            }
        }
    }
    __syncthreads();

    // coalesced vector store: 16B per lane (+ optional fused adj)
    constexpr int VEC = 16 / sizeof(TC);
#pragma unroll
    for (int c = tid; c < BM*(BN/VEC); c += NT) {
        int row = c / (BN/VEC), col = (c % (BN/VEC)) * VEC;
        size_t gidx = (size_t)g*sCg + (size_t)(m0+row)*ldc + n0 + col;
        *(float4*)&C[gidx] = *(const float4*)&Cs[row*LDC + col];
        if constexpr (FUSE_ADJ) {
            float4 cv = *(const float4*)&Cs[row*LDC + col];
            float4 g4 = *(const float4*)&gn[gidx];
            float4 a4;
            a4.x = 1.0f / (1.0f + __expf(-(cv.x + g4.x)));
            a4.y = 1.0f / (1.0f + __expf(-(cv.y + g4.y)));
            a4.z = 1.0f / (1.0f + __expf(-(cv.z + g4.z)));
            a4.w = 1.0f / (1.0f + __expf(-(cv.w + g4.w)));
            *(float4*)&adjout[gidx] = a4;
        }
    }
}

// ---------------- MFMA fused attention on packed QKV [8192][1536] ----------
// K staged in LDS (shared across the 4 waves); V^T staged; O via Ps re-use.
__global__ __launch_bounds__(256) void attn_mfma(bf16* __restrict__ QKV)
{
    __shared__ bf16 Ps[NN][NN + 8];
    __shared__ bf16 Ks[NN][DHH + 8];
    __shared__ bf16 Vt[DHH][NN + 8];
    int bh = blockIdx.x;
    int h = bh & (HH - 1);
    int b = bh >> 3;
    const int tid = threadIdx.x;
    const int lane = tid & 63;
    const int w = tid >> 6;
    const int lr = lane & 15;
    const int lq = lane >> 4;
    const size_t baseQ = (size_t)(b * NN) * LDQKV + h * DHH;
    const size_t baseK = baseQ + 512;
    const size_t baseV = baseQ + 1024;

    // stage K rows (coalesced float4)
    for (int c = tid; c < NN * (DHH/8); c += 256) {
        int row = c >> 3, d8 = (c & 7) * 8;
        *(float4*)&Ks[row][d8] =
            *(const float4*)(QKV + baseK + (size_t)row * LDQKV + d8);
    }
    // stage V^T (u32-paired writes)
    for (int c = tid; c < 512; c += 256) {
        int m = (c >> 3) * 2;
        int d8 = (c & 7) * 8;
        F4B8 v0, v1;
        v0.f = *(const float4*)(QKV + baseV + (size_t)m * LDQKV + d8);
        v1.f = *(const float4*)(QKV + baseV + (size_t)(m + 1) * LDQKV + d8);
#pragma unroll
        for (int j = 0; j < 8; j++) {
            B2U pk; pk.h[0] = v0.h[j]; pk.h[1] = v1.h[j];
            *(unsigned int*)&Vt[d8 + j][m] = pk.u;
        }
    }
    __syncthreads();

    f32x4v sacc[2][8];
#pragma unroll
    for (int mi = 0; mi < 2; mi++)
#pragma unroll
        for (int ni = 0; ni < 8; ni++)
            sacc[mi][ni] = (f32x4v){0.f, 0.f, 0.f, 0.f};
#pragma unroll
    for (int ks = 0; ks < 2; ks++) {
        short8v aq[2];
#pragma unroll
        for (int mi = 0; mi < 2; mi++) {
            int row = w * 32 + mi * 16 + lr;
            aq[mi] = *(const short8v*)(QKV + baseQ + (size_t)row * LDQKV + ks * 32 + lq * 8);
        }
#pragma unroll
        for (int ni = 0; ni < 8; ni++) {
            short8v bk = *(const short8v*)&Ks[ni * 16 + lr][ks * 32 + lq * 8];
#pragma unroll
            for (int mi = 0; mi < 2; mi++)
                sacc[mi][ni] = __builtin_amdgcn_mfma_f32_16x16x32_bf16(
                    aq[mi], bk, sacc[mi][ni], 0, 0, 0);
        }
    }

#pragma unroll
    for (int mi = 0; mi < 2; mi++) {
#pragma unroll
        for (int r = 0; r < 4; r++) {
            float mx = -1e30f;
#pragma unroll
            for (int ni = 0; ni < 8; ni++)
                mx = fmaxf(mx, sacc[mi][ni][r]);
            mx = fmaxf(mx, __shfl_xor(mx, 1, 64));
            mx = fmaxf(mx, __shfl_xor(mx, 2, 64));
            mx = fmaxf(mx, __shfl_xor(mx, 4, 64));
            mx = fmaxf(mx, __shfl_xor(mx, 8, 64));
            mx *= 0.125f;
            float s = 0.f;
#pragma unroll
            for (int ni = 0; ni < 8; ni++) {
                float e = __expf(sacc[mi][ni][r] * 0.125f - mx);
                sacc[mi][ni][r] = e; s += e;
            }
            s += __shfl_xor(s, 1, 64);
            s += __shfl_xor(s, 2, 64);
            s += __shfl_xor(s, 4, 64);
            s += __shfl_xor(s, 8, 64);
            float inv = 1.0f / s;
            int row = w * 32 + mi * 16 + lq * 4 + r;
#pragma unroll
            for (int ni = 0; ni < 8; ni++)
                Ps[row][ni * 16 + lr] = f2b(sacc[mi][ni][r] * inv);
        }
    }
    __syncthreads();

    f32x4v oacc[2][4];
#pragma unroll
    for (int mi = 0; mi < 2; mi++)
#pragma unroll
        for (int ni = 0; ni < 4; ni++)
            oacc[mi][ni] = (f32x4v){0.f, 0.f, 0.f, 0.f};
#pragma unroll
    for (int ks = 0; ks < 4; ks++) {
        short8v ap[2];
#pragma unroll
        for (int mi = 0; mi < 2; mi++)
            ap[mi] = *(const short8v*)&Ps[w * 32 + mi * 16 + lr][ks * 32 + lq * 8];
#pragma unroll
        for (int ni = 0; ni < 4; ni++) {
            short8v bv = *(const short8v*)&Vt[ni * 16 + lr][ks * 32 + lq * 8];
#pragma unroll
            for (int mi = 0; mi < 2; mi++)
                oacc[mi][ni] = __builtin_amdgcn_mfma_f32_16x16x32_bf16(
                    ap[mi], bv, oacc[mi][ni], 0, 0, 0);
        }
    }
    __syncthreads();           // Ps fragment reads done — reuse Ps as O tile
#pragma unroll
    for (int mi = 0; mi < 2; mi++)
#pragma unroll
        for (int ni = 0; ni < 4; ni++) {
            int d = ni * 16 + lr;
#pragma unroll
            for (int r = 0; r < 4; r++) {
                int row = w * 32 + mi * 16 + lq * 4 + r;
                Ps[row][d] = f2b(oacc[mi][ni][r]);
            }
        }
    __syncthreads();
    for (int c = tid; c < NN * (DHH/8); c += 256) {
        int row = c >> 3, d8 = (c & 7) * 8;
        *(float4*)(QKV + baseQ + (size_t)row * LDQKV + d8) = *(const float4*)&Ps[row][d8];
    }
}

// ---------------- add+LN: one wave per token; R has stride ldr ------------
__global__ __launch_bounds__(256) void add_ln_kernel(
    bf16* __restrict__ X, const bf16* __restrict__ R, int ldr,
    const float* __restrict__ g, const float* __restrict__ bt)
{
    int tok = blockIdx.x * 4 + (threadIdx.x >> 6);
    int lane = threadIdx.x & 63;
    size_t base = (size_t)tok * DD + lane * 8;
    size_t rbase = (size_t)tok * ldr + lane * 8;
    F4B8 x, r;
    x.f = *(const float4*)&X[base];
    r.f = *(const float4*)&R[rbase];
    float v[8]; float s = 0.f, s2 = 0.f;
#pragma unroll
    for (int j = 0; j < 8; j++) {
        v[j] = b2f(x.h[j]) + b2f(r.h[j]);
        s += v[j]; s2 += v[j] * v[j];
    }
#pragma unroll
    for (int m = 1; m < 64; m <<= 1) {
        s  += __shfl_xor(s, m, 64);
        s2 += __shfl_xor(s2, m, 64);
    }
    float mean = s * (1.0f / 512.0f);
    float var = fmaxf(s2 * (1.0f / 512.0f) - mean * mean, 0.0f);
    float rstd = rsqrtf(var + 1e-5f);
    alignas(16) float gv[8], bv[8];
    *(float4*)&gv[0] = *(const float4*)&g[lane * 8];
    *(float4*)&gv[4] = *(const float4*)&g[lane * 8 + 4];
    *(float4*)&bv[0] = *(const float4*)&bt[lane * 8];
    *(float4*)&bv[4] = *(const float4*)&bt[lane * 8 + 4];
    F4B8 o;
#pragma unroll
    for (int j = 0; j < 8; j++)
        o.h[j] = f2b((v[j] - mean) * rstd * gv[j] + bv[j]);
    *(float4*)&X[base] = o.f;
}

// ---------------- hyper-network ----------------
__global__ __launch_bounds__(512) void hyper_kernel(
    const int* __restrict__ idx, const float* __restrict__ emb,
    const float* __restrict__ W1, const float* __restrict__ b1,
    const float* __restrict__ W2, const float* __restrict__ b2,
    float* __restrict__ MODp)
{
    int b = blockIdx.x;
    int t = threadIdx.x;
    __shared__ float instr[EE];
    __shared__ float h1[HID];
    int id = idx[b];
    if (t < EE) instr[t] = emb[id*EE + t];
    __syncthreads();
    if (t < HID) {
        float a = b1[t];
        for (int i = 0; i < EE; i++) a += instr[i] * W1[i*HID + t];
        h1[t] = gelu_f(a);
    }
    __syncthreads();
    float a = b2[t];
    for (int i = 0; i < HID; i++) a += h1[i] * W2[i*DD + t];
    MODp[(size_t)b*DD + t] = a;
}

// ---------------- deltas: one wave per (n,b) row ----------------
__global__ __launch_bounds__(256) void deltas_kernel(
    const bf16* __restrict__ HE, const float* __restrict__ W2,
    const float* __restrict__ b2, float* __restrict__ out)
{
    int rid = blockIdx.x * 4 + (threadIdx.x >> 6);
    int lane = threadIdx.x & 63;
    int n = rid >> 6;
    int b = rid & 63;
    const bf16* hrow = HE + ((size_t)n * BB + b) * DD + lane * 8;
    const float* wrow = W2 + (size_t)n * DD + lane * 8;
    F4B8 hv; hv.f = *(const float4*)hrow;
    alignas(16) float wv[8];
    *(float4*)&wv[0] = *(const float4*)&wrow[0];
    *(float4*)&wv[4] = *(const float4*)&wrow[4];
    float s = 0.f;
#pragma unroll
    for (int j = 0; j < 8; j++) s += b2f(hv.h[j]) * wv[j];
#pragma unroll
    for (int m = 1; m < 64; m <<= 1) s += __shfl_xor(s, m, 64);
    if (lane == 0) out[b * NN + n] = s + b2[n];
}

// ---------------- host-side GEMM dispatch helper ----------------
template<int BM,int BN,int WM,int WN,int ACT,bool HB,typename TC>
static inline void launch2(bool useT, dim3 grid, hipStream_t s,
    const bf16* A, const float* Wf, const bf16* Wt, const float* bias, TC* C,
    int K, int lda, int ldbF, int ldbT, int ldc,
    long long sAg, long long sBg, long long sbg, long long sCg)
{
    if (useT)
        gemm2<BM,BN,WM,WN,ACT,true ,HB,false,false,bf16 ,TC><<<grid,WM*WN*64,0,s>>>(
            A, Wt, bias, C, K, lda, ldbT, ldc, sAg,sBg,sbg,sCg,
            nullptr, nullptr, nullptr);
    else
        gemm2<BM,BN,WM,WN,ACT,false,HB,false,false,float,TC><<<grid,WM*WN*64,0,s>>>(
            A, Wf, bias, C, K, lda, ldbF, ldc, sAg,sBg,sbg,sCg,
            nullptr, nullptr, nullptr);
}

// =========================== host side ===========================
extern "C" void kernel_launch(void* const* d_in, const int* in_sizes, int n_in,
                              void* d_out, int out_size, void* d_ws, size_t ws_size,
                              hipStream_t stream)
{
    const float* base_s = (const float*)d_in[0];
    const float* int_s  = (const float*)d_in[1];
    const float* targ   = (const float*)d_in[2];
    const float* maskv  = (const float*)d_in[3];
    const int*   nidx   = (const int*)  d_in[4];
    const float* gnoise = (const float*)d_in[5];
    const float* encW = (const float*)d_in[6];
    const float* encB = (const float*)d_in[7];
    const float* Wq = (const float*)d_in[8];  const float* bq = (const float*)d_in[9];
    const float* Wk = (const float*)d_in[10]; const float* bk = (const float*)d_in[11];
    const float* Wv = (const float*)d_in[12]; const float* bv = (const float*)d_in[13];
    const float* Wo = (const float*)d_in[14]; const float* bo = (const float*)d_in[15];
    const float* ln1g = (const float*)d_in[16]; const float* ln1b = (const float*)d_in[17];
    const float* Wff1 = (const float*)d_in[18]; const float* bff1 = (const float*)d_in[19];
    const float* Wff2 = (const float*)d_in[20]; const float* bff2 = (const float*)d_in[21];
    const float* ln2g = (const float*)d_in[22]; const float* ln2b = (const float*)d_in[23];
    const float* emb  = (const float*)d_in[24];
    const float* hW1 = (const float*)d_in[25]; const float* hb1 = (const float*)d_in[26];
    const float* hW2 = (const float*)d_in[27]; const float* hb2 = (const float*)d_in[28];
    const float* eW1 = (const float*)d_in[29]; const float* eb1 = (const float*)d_in[30];
    const float* eW2 = (const float*)d_in[31]; const float* eb2 = (const float*)d_in[32];
    const float* dpW = (const float*)d_in[33]; const float* dpB = (const float*)d_in[34];
    const float* dcW = (const float*)d_in[35]; const float* dcB = (const float*)d_in[36];

    float* out_deltas = (float*)d_out;
    float* out_logits = out_deltas + (size_t)BB*NN;
    float* out_adj    = out_logits + (size_t)BB*NN*NN;

    const size_t SZ = (size_t)NTOK * DD;     // 4,194,304 elements

    const size_t WT_ELEMS = (size_t)3*LL*DD*DD + (size_t)LL*DD*DD
                          + 2*(size_t)LL*DD*DFF + 2*(size_t)DD*DD;  // 13,107,200
    const size_t NEED_BIG = 6*SZ*2 + (size_t)BB*DD*4;
    const size_t NEED_P0  = NEED_BIG + WT_ELEMS*2 + (LL*LDQKV + 1024)*4;
    const bool big = ws_size >= NEED_BIG;
    const bool p0  = ws_size >= NEED_P0;

    bf16* X  = (bf16*)d_ws;
    bf16* PK = X + SZ;                 // packed QKV / Hid / DAG / scratch
    bf16* F2 = PK + 4*SZ;              // big only
    float* MODp = big ? (float*)(F2 + SZ) : (float*)(PK + 3*SZ);

    bf16 *wqkvT=nullptr,*woT=nullptr,*wf1T=nullptr,*wf2T=nullptr,*dagT=nullptr;
    float *qkvB=nullptr,*dagB=nullptr;
    if (p0) {
        bf16* WT = (bf16*)(MODp + (size_t)BB*DD);
        wqkvT = WT;                                 // [L][1536][512]
        woT   = wqkvT + (size_t)3*LL*DD*DD;         // [L][512][512]
        wf1T  = woT + (size_t)LL*DD*DD;             // [L][2048][512]
        wf2T  = wf1T + (size_t)LL*DD*DFF;           // [L][512][2048]
        dagT  = wf2T + (size_t)LL*DD*DFF;           // [1024][512]
        qkvB  = (float*)(dagT + 2*(size_t)DD*DD);
        dagB  = qkvB + LL*LDQKV;

        TXJobs J;
        int acc = 0;
        auto addjob = [&](int j, const float* in, bf16* out, int K, int N,
                          long long sIn, long long sOut, int G) {
            J.in[j]=in; J.out[j]=out; J.K[j]=K; J.N[j]=N; J.sIn[j]=sIn; J.sOut[j]=sOut;
            acc += G * (K>>5) * (N>>5); J.tileEnd[j]=acc;
        };
        addjob(0, Wq,  wqkvT,          DD, DD, (long long)DD*DD, (long long)LDQKV*DD, LL);
        addjob(1, Wk,  wqkvT+512*512,  DD, DD, (long long)DD*DD, (long long)LDQKV*DD, LL);
        addjob(2, Wv,  wqkvT+1024*512, DD, DD, (long long)DD*DD, (long long)LDQKV*DD, LL);
        addjob(3, Wo,  woT,            DD, DD, (long long)DD*DD, (long long)DD*DD,    LL);
        addjob(4, Wff1,wf1T,           DD, DFF,(long long)DD*DFF,(long long)DD*DFF,   LL);
        addjob(5, Wff2,wf2T,           DFF,DD, (long long)DD*DFF,(long long)DD*DFF,   LL);
        addjob(6, dpW, dagT,           DD, DD, 0, 0, 1);
        addjob(7, dcW, dagT+512*512,   DD, DD, 0, 0, 1);
        transpose_all<<<acc, 256, 0, stream>>>(J);
        pack_bias<<<(LL*LDQKV + 1024 + 255)/256, 256, 0, stream>>>(
            bq, bk, bv, dpB, dcB, qkvB, dagB);
    }

    encoder_kernel<<<NTOK*DD/8/256, 256, 0, stream>>>(
        base_s, int_s, targ, maskv, encW, encB, X);

    for (int l = 0; l < LL; ++l) {
        const size_t od = (size_t)l*DD*DD, of1 = (size_t)l*DD*DFF;
        // QKV -> packed PK [8192][1536]
        if (p0) {
            gemm2<128,128,2,4,0,true,true,false,false,bf16,bf16><<<dim3(12,64,1),512,0,stream>>>(
                X, wqkvT + (size_t)l*LDQKV*DD, qkvB + (size_t)l*LDQKV, PK,
                DD, DD, DD, LDQKV, 0,0,0,0, nullptr, nullptr, nullptr);
        } else {
            gemm2<128,128,2,4,0,false,true,false,false,float,bf16><<<dim3(4,64,1),512,0,stream>>>(
                X, Wq+od, bq+(size_t)l*DD, PK,        DD, DD, DD, LDQKV, 0,0,0,0,
                nullptr, nullptr, nullptr);
            gemm2<128,128,2,4,0,false,true,false,false,float,bf16><<<dim3(4,64,1),512,0,stream>>>(
                X, Wk+od, bk+(size_t)l*DD, PK+512,    DD, DD, DD, LDQKV, 0,0,0,0,
                nullptr, nullptr, nullptr);
            gemm2<128,128,2,4,0,false,true,false,false,float,bf16><<<dim3(4,64,1),512,0,stream>>>(
                X, Wv+od, bv+(size_t)l*DD, PK+1024,   DD, DD, DD, LDQKV, 0,0,0,0,
                nullptr, nullptr, nullptr);
        }
        attn_mfma<<<BB*HH, 256, 0, stream>>>(PK);   // O in place over Q slice
        // O-proj: BM=64 -> grid (4,128)=512 blocks (2 blocks/CU)
        launch2<64,128,2,4,0,true,bf16>(p0, dim3(4,128,1), stream,
            PK, Wo+od, woT+od, bo+(size_t)l*DD, PK+512, DD, LDQKV, DD, DD, LDQKV, 0,0,0,0);
        add_ln_kernel<<<NTOK/4, 256, 0, stream>>>(X, PK+512, LDQKV,
            ln1g+(size_t)l*DD, ln1b+(size_t)l*DD);

        if (big) {
            launch2<128,128,2,4,1,true,bf16>(p0, dim3(16,64,1), stream,
                X, Wff1+of1, wf1T+of1, bff1+(size_t)l*DFF, PK,
                DD, DD, DFF, DD, DFF, 0,0,0,0);
            // FFN2: BM=64 -> grid (4,128)=512 blocks (2 blocks/CU)
            launch2<64,128,2,4,0,true,bf16>(p0, dim3(4,128,1), stream,
                PK, Wff2+of1, wf2T+of1, bff2+(size_t)l*DD, F2,
                DFF, DFF, DD, DFF, DD, 0,0,0,0);
            add_ln_kernel<<<NTOK/4, 256, 0, stream>>>(X, F2, DD,
                ln2g+(size_t)l*DD, ln2b+(size_t)l*DD);
        } else {
            for (int c = 0; c < 4; ++c) {
                launch2<128,128,2,4,1,true,bf16>(p0, dim3(16,16,1), stream,
                    X + (size_t)c*2048*DD, Wff1+of1, wf1T+of1, bff1+(size_t)l*DFF, PK,
                    DD, DD, DFF, DD, DFF, 0,0,0,0);
                launch2<64,128,2,4,0,true,bf16>(p0, dim3(4,32,1), stream,
                    PK, Wff2+of1, wf2T+of1, bff2+(size_t)l*DD, PK + 2*SZ + (size_t)c*2048*DD,
                    DFF, DFF, DD, DFF, DD, 0,0,0,0);
            }
            add_ln_kernel<<<NTOK/4, 256, 0, stream>>>(X, PK + 2*SZ, DD,
                ln2g+(size_t)l*DD, ln2b+(size_t)l*DD);
        }
    }

    hyper_kernel<<<BB, 512, 0, stream>>>(nidx, emb, hW1, hb1, hW2, hb2, MODp);

    // per-node experts: grouped 64x512x512, f32-B path, fused xm (ASCALE)
    bf16* HEb = PK;
    gemm2<64,128,2,2,1,false,true,true,false,float,bf16><<<dim3(4,1,NN),256,0,stream>>>(
        X, eW1, eb1, HEb, DD, NN*DD, DD, DD,
        DD, (long long)DD*DD, DD, (long long)BB*DD, MODp, nullptr, nullptr);
    deltas_kernel<<<NN*BB/4, 256, 0, stream>>>(HEb, eW2, eb2, out_deltas);

    // DAG heads -> packed [8192][1024] in PK (after deltas consumed HE)
    bf16* DAGb = PK;
    if (p0) {
        gemm2<128,128,2,4,0,true,true,false,false,bf16,bf16><<<dim3(8,64,1),512,0,stream>>>(
            X, dagT, dagB, DAGb, DD, DD, DD, 1024, 0,0,0,0, nullptr, nullptr, nullptr);
    } else {
        gemm2<128,128,2,4,0,false,true,false,false,float,bf16><<<dim3(4,64,1),512,0,stream>>>(
            X, dpW, dpB, DAGb,       DD, DD, DD, 1024, 0,0,0,0, nullptr, nullptr, nullptr);
        gemm2<128,128,2,4,0,false,true,false,false,float,bf16><<<dim3(4,64,1),512,0,stream>>>(
            X, dcW, dcB, DAGb + 512, DD, DD, DD, 1024, 0,0,0,0, nullptr, nullptr, nullptr);
    }
    // logits[b] = P[b] @ C[b]^T, f32 into d_out; adj fused in epilogue
    gemm2<64,64,2,2,0,true,false,false,true,bf16,float><<<dim3(2,2,BB),256,0,stream>>>(
        DAGb, DAGb + 512, (const float*)nullptr, out_logits,
        DD, 1024, 1024, NN,
        (long long)NN*1024, (long long)NN*1024, 0, (long long)NN*NN,
        nullptr, gnoise, out_adj);

    (void)in_sizes; (void)n_in; (void)out_size;
}

// Round 14
// 547.910 us; speedup vs baseline: 1.0885x; 1.0002x over previous
//
#include <hip/hip_runtime.h>
#include <hip/hip_bf16.h>
#include <math.h>

// ---- problem constants ----
#define BB 64
#define NN 128
#define DD 512
#define DFF 2048
#define HH 8
#define DHH 64
#define EE 32
#define HID 64
#define LL 4
#define NTOK (BB*NN)          // 8192
#define LDQKV 1536

typedef __hip_bfloat16 bf16;
typedef __attribute__((ext_vector_type(8))) short short8v;   // 8 bf16 (4 VGPRs)
typedef __attribute__((ext_vector_type(4))) float f32x4v;    // 4 f32 acc

__device__ __forceinline__ float b2f(bf16 x) { return __bfloat162float(x); }
__device__ __forceinline__ bf16 f2b(float x) { return __float2bfloat16(x); }
__device__ __forceinline__ float gelu_f(float x) {
    return 0.5f * x * (1.0f + erff(x * 0.7071067811865476f));
}
// async global->LDS, 16B/lane; LDS dest is wave-uniform base + lane*16
__device__ __forceinline__ void glds16(const bf16* g, bf16* l) {
    __builtin_amdgcn_global_load_lds(
        (const __attribute__((address_space(1))) unsigned int*)g,
        (__attribute__((address_space(3))) unsigned int*)l,
        16, 0, 0);
}

union F4B8 { float4 f; bf16 h[8]; };
union B2U { bf16 h[2]; unsigned int u; };

// ---------------- merged weight prep: 8 transpose jobs in one launch -------
#define NJOBS 8
struct TXJobs {
    const float* in[NJOBS];
    bf16* out[NJOBS];
    int K[NJOBS], N[NJOBS];
    long long sIn[NJOBS], sOut[NJOBS];
    int tileEnd[NJOBS];          // inclusive prefix sum of G*(K/32)*(N/32)
};
__global__ __launch_bounds__(256) void transpose_all(TXJobs jobs)
{
    __shared__ float t[32][33];
    int tile = blockIdx.x;
    int j = 0;
    while (j < NJOBS - 1 && tile >= jobs.tileEnd[j]) ++j;
    int base = j ? jobs.tileEnd[j-1] : 0;
    int local = tile - base;
    const int K = jobs.K[j], N = jobs.N[j];
    const int tpg = (K >> 5) * (N >> 5);
    int g  = local / tpg;
    int r  = local % tpg;
    int tX = r % (N >> 5), tY = r / (N >> 5);
    const float* in = jobs.in[j] + (size_t)g * jobs.sIn[j];
    bf16* out = jobs.out[j] + (size_t)g * jobs.sOut[j];
    int n0 = tX * 32, k0 = tY * 32;
    int tx = threadIdx.x & 31, ty = threadIdx.x >> 5;
#pragma unroll
    for (int i = 0; i < 32; i += 8)
        t[ty + i][tx] = in[(size_t)(k0 + ty + i) * N + n0 + tx];
    __syncthreads();
#pragma unroll
    for (int i = 0; i < 32; i += 8)
        out[(size_t)(n0 + ty + i) * K + k0 + tx] = f2b(t[tx][ty + i]);
}

// merged bias packing: qkvB [L][1536] then dagB [1024]
__global__ __launch_bounds__(256) void pack_bias(
    const float* __restrict__ bq, const float* __restrict__ bk,
    const float* __restrict__ bv, const float* __restrict__ dp,
    const float* __restrict__ dc, float* __restrict__ qkvB,
    float* __restrict__ dagB)
{
    int i = blockIdx.x * 256 + threadIdx.x;
    if (i < LL * LDQKV) {
        int l = i / LDQKV, j = i % LDQKV;
        float v = (j < 512) ? bq[l*512 + j]
                : (j < 1024 ? bk[l*512 + j - 512] : bv[l*512 + j - 1024]);
        qkvB[i] = v;
    } else if (i < LL * LDQKV + 1024) {
        int j = i - LL * LDQKV;
        dagB[j] = (j < 512) ? dp[j] : dc[j - 512];
    }
}

// ---------------- encoder ----------------
__global__ __launch_bounds__(256) void encoder_kernel(
    const float* __restrict__ bs, const float* __restrict__ ins,
    const float* __restrict__ tr, const float* __restrict__ im,
    const float* __restrict__ encW, const float* __restrict__ encB,
    bf16* __restrict__ X)
{
    int idx = blockIdx.x * 256 + threadIdx.x;
    size_t i8 = (size_t)idx * 8;
    int d0 = (int)(i8 & (DD - 1));
    int t  = (int)(i8 >> 9);
    float f0 = bs[t], f1 = ins[t], f2 = tr[t], f3 = im[t];
    alignas(16) float acc[8], w[8];
    *(float4*)&acc[0] = *(const float4*)&encB[d0];
    *(float4*)&acc[4] = *(const float4*)&encB[d0 + 4];
    const float fs[4] = {f0, f1, f2, f3};
#pragma unroll
    for (int k = 0; k < 4; k++) {
        *(float4*)&w[0] = *(const float4*)&encW[k * DD + d0];
        *(float4*)&w[4] = *(const float4*)&encW[k * DD + d0 + 4];
#pragma unroll
        for (int j = 0; j < 8; j++) acc[j] = fmaf(fs[k], w[j], acc[j]);
    }
    F4B8 o;
#pragma unroll
    for (int j = 0; j < 8; j++) o.h[j] = f2b(acc[j]);
    *(float4*)&X[i8] = o.f;
}

// ---------------- deltas init: out[b*NN+n] = eb2[n] ----------------
__global__ __launch_bounds__(256) void deltas_init(
    const float* __restrict__ b2, float* __restrict__ out)
{
    int i = blockIdx.x * 256 + threadIdx.x;
    if (i < BB * NN) out[i] = b2[i & (NN - 1)];
}

// ---------------- MFMA GEMM ----------------
// TRANSB (bf16 [N][K]): m97 structure — global_load_lds staging, pre-swizzled
// source, linear LDS, 2-buffer, 1 barrier / K-step (round-10 proven form).
// !TRANSB (f32 [K][N]): reg-staged dbuf with transpose+cvt (expert GEMM);
//   ASCALE multiplies A by modp[row*DD + k] during commit (fused xm).
// FUSE_ADJ: epilogue also writes adj = sigmoid(C + gn) (logits GEMM).
// FUSE_DELTA: epilogue computes per-row dot with gn(=eW2 slice) and
//   atomicAdds into adjout(=out_deltas); global C write SKIPPED.
template<int BM,int BN,int WM,int WN,int ACT,bool TRANSB,bool HAS_BIAS,
         bool ASCALE,bool FUSE_ADJ,bool FUSE_DELTA,typename TB,typename TC>
__global__ __launch_bounds__(WM*WN*64) void gemm2(
    const bf16* __restrict__ A, const TB* __restrict__ Bw,
    const float* __restrict__ bias, TC* __restrict__ C,
    int K, int lda, int ldb, int ldc,
    long long sAg, long long sBg, long long sbg, long long sCg,
    const float* __restrict__ modp, const float* __restrict__ gn,
    float* __restrict__ adjout)
{
    constexpr int BK = 64;
    constexpr int NT = WM*WN*64;
    constexpr int NW = NT/64;
    constexpr int MI = BM/WM/16;
    constexpr int NI = BN/WN/16;
    constexpr int LDK = TRANSB ? BK : (BK + 8);
    constexpr int LDC = BN + 8;
    constexpr size_t SH_AB = (size_t)2*(BM+BN)*LDK*sizeof(bf16);
    constexpr size_t SH_C  = (size_t)BM*LDC*sizeof(TC);
    __shared__ __align__(16) char smem[(SH_AB > SH_C ? SH_AB : SH_C)];
    bf16* AsB = (bf16*)smem;                 // [2][BM][LDK]
    bf16* BsB = AsB + (size_t)2*BM*LDK;      // [2][BN][LDK]
    TC*   Cs  = (TC*)smem;                   // [BM][LDC]

    const int g = blockIdx.z;
    const bf16* Ag = A + (size_t)g * sAg;
    const TB*   Bg = Bw + (size_t)g * sBg;

    // XCD-chunked swizzle (bijective when nwg % 8 == 0; skip grouped)
    int bx = blockIdx.x, by = blockIdx.y;
    if (gridDim.z == 1) {
        int nwg = gridDim.x * gridDim.y;
        if ((nwg & 7) == 0) {
            int id = by * gridDim.x + bx;
            id = (id & 7) * (nwg >> 3) + (id >> 3);
            bx = id % gridDim.x;
            by = id / gridDim.x;
        }
    }
    const int m0 = by * BM, n0 = bx * BN;
    const int tid = threadIdx.x, lane = tid & 63, wid = tid >> 6;
    const int wm = wid / WN, wn = wid % WN;
    const int lr = lane & 15, lq = lane >> 4;
    const int KT = K / BK;

    f32x4v acc[MI][NI];
#pragma unroll
    for (int mi = 0; mi < MI; mi++)
#pragma unroll
        for (int ni = 0; ni < NI; ni++)
            acc[mi][ni] = (f32x4v){0.f, 0.f, 0.f, 0.f};

    if constexpr (TRANSB) {
        // ---- m97-style: glds direct staging, pre-swizzled source ----
        auto stage = [&](int kt, int p) {
#pragma unroll
            for (int q = wid; q < BM/8; q += NW) {
                int r = q*8 + (lane >> 3), sp = lane & 7;
                glds16(Ag + (size_t)(m0 + r)*lda + kt*BK + ((sp ^ (r & 7)) << 3),
                       AsB + ((size_t)p*BM + q*8)*BK);
            }
#pragma unroll
            for (int q = wid; q < BN/8; q += NW) {
                int r = q*8 + (lane >> 3), sp = lane & 7;
                glds16((const bf16*)Bg + (size_t)(n0 + r)*ldb + kt*BK + ((sp ^ (r & 7)) << 3),
                       BsB + ((size_t)p*BN + q*8)*BK);
            }
        };
        stage(0, 0);
        __syncthreads();
        const int rx7 = lr & 7;
        int p = 0;
        for (int kt = 0; kt < KT; ++kt) {
            if (kt + 1 < KT) stage(kt + 1, p ^ 1);   // in flight during MFMA
#pragma unroll
            for (int kk = 0; kk < 2; ++kk) {
                const int colo = ((((kk << 2) | lq) ^ rx7) << 3);
                short8v av[MI], bv[NI];
#pragma unroll
                for (int mi = 0; mi < MI; ++mi) {
                    int row = wm*(BM/WM) + mi*16 + lr;
                    av[mi] = *(const short8v*)&AsB[((size_t)p*BM + row)*BK + colo];
                }
#pragma unroll
                for (int ni = 0; ni < NI; ++ni) {
                    int row = wn*(BN/WN) + ni*16 + lr;
                    bv[ni] = *(const short8v*)&BsB[((size_t)p*BN + row)*BK + colo];
                }
#pragma unroll
                for (int mi = 0; mi < MI; ++mi)
#pragma unroll
                    for (int ni = 0; ni < NI; ++ni)
                        acc[mi][ni] = __builtin_amdgcn_mfma_f32_16x16x32_bf16(
                            av[mi], bv[ni], acc[mi][ni], 0, 0, 0);
            }
            __syncthreads();   // drains glds (vmcnt) + frag reads; swap buffers
            p ^= 1;
        }
    } else {
        // ---- f32-B path: reg-staged dbuf with transpose+cvt ----
        constexpr int RA  = (BM*(BK/8))/NT;
        constexpr int RBF = (BK*(BN/4))/NT;
        float4 rA[RA];
        float4 rF[RBF];
        int staged_kt = 0;
        auto issue = [&](int kt) {
            staged_kt = kt;
#pragma unroll
            for (int r = 0; r < RA; ++r) {
                int c = tid + r*NT; int row = c >> 3, k8 = (c & 7) << 3;
                rA[r] = *(const float4*)(Ag + (size_t)(m0+row)*lda + kt*BK + k8);
            }
#pragma unroll
            for (int r = 0; r < RBF; ++r) {
                int c = tid + r*NT; int kk = c/(BN/4), n4 = (c%(BN/4))*4;
                rF[r] = *(const float4*)((const float*)Bg + (size_t)(kt*BK+kk)*ldb + n0 + n4);
            }
        };
        auto commit = [&](int p) {
#pragma unroll
            for (int r = 0; r < RA; ++r) {
                int c = tid + r*NT; int row = c >> 3, k8 = (c & 7) << 3;
                if constexpr (ASCALE) {
                    F4B8 u; u.f = rA[r];
                    alignas(16) float m8[8];
                    const float* mp = modp + (size_t)(m0+row)*DD + staged_kt*BK + k8;
                    *(float4*)&m8[0] = *(const float4*)mp;
                    *(float4*)&m8[4] = *(const float4*)(mp + 4);
#pragma unroll
                    for (int jj = 0; jj < 8; ++jj)
                        u.h[jj] = f2b(b2f(u.h[jj]) * m8[jj]);
                    *(float4*)&AsB[((size_t)p*BM + row)*LDK + k8] = u.f;
                } else {
                    *(float4*)&AsB[((size_t)p*BM + row)*LDK + k8] = rA[r];
                }
            }
#pragma unroll
            for (int r = 0; r < RBF; ++r) {
                int c = tid + r*NT; int kk = c/(BN/4), n4 = (c%(BN/4))*4;
                int kg = kk >> 3, kw = kk & 7;
                alignas(16) float vv[4]; *(float4*)vv = rF[r];
#pragma unroll
                for (int i = 0; i < 4; ++i) {
                    int n = n4 + i;
                    BsB[((size_t)p*BN + n)*LDK + (((kg ^ ((n>>2)&7)) << 3) | kw)] = f2b(vv[i]);
                }
            }
        };
        issue(0); commit(0); __syncthreads();
        for (int kt = 0; kt < KT; ++kt) {
            if (kt + 1 < KT) issue(kt + 1);
            const int p = kt & 1;
#pragma unroll
            for (int kk = 0; kk < 2; ++kk) {
                short8v av[MI], bv[NI];
#pragma unroll
                for (int mi = 0; mi < MI; ++mi) {
                    int row = wm*(BM/WM) + mi*16 + lr;
                    av[mi] = *(const short8v*)&AsB[((size_t)p*BM + row)*LDK + kk*32 + lq*8];
                }
#pragma unroll
                for (int ni = 0; ni < NI; ++ni) {
                    int row = wn*(BN/WN) + ni*16 + lr;
                    int col = (((kk*4 + lq) ^ ((row>>2)&7)) << 3);
                    bv[ni] = *(const short8v*)&BsB[((size_t)p*BN + row)*LDK + col];
                }
#pragma unroll
                for (int mi = 0; mi < MI; ++mi)
#pragma unroll
                    for (int ni = 0; ni < NI; ++ni)
                        acc[mi][ni] = __builtin_amdgcn_mfma_f32_16x16x32_bf16(
                            av[mi], bv[ni], acc[mi][ni], 0, 0, 0);
            }
            if (kt + 1 < KT) { commit((kt + 1) & 1); }
            __syncthreads();
        }
    }
    __syncthreads();     // safe to reuse smem as C tile

    // stage C (bias + act) into LDS
#pragma unroll
    for (int mi = 0; mi < MI; ++mi) {
        int rb = wm*(BM/WM) + mi*16 + lq*4;
#pragma unroll
        for (int ni = 0; ni < NI; ++ni) {
            int cc = wn*(BN/WN) + ni*16 + lr;
            float bvv = 0.f;
            if constexpr (HAS_BIAS) bvv = bias[(size_t)g*sbg + n0 + cc];
#pragma unroll
            for (int r = 0; r < 4; ++r) {
                float v = acc[mi][ni][r] + bvv;
                if (ACT == 1) v = gelu_f(v);
                if constexpr (sizeof(TC) == 2) Cs[(rb+r)*LDC + cc] = (TC)f2b(v);
                else ((float*)Cs)[(rb+r)*LDC + cc] = v;
            }
        }
    }
    __syncthreads();

    if constexpr (FUSE_DELTA) {
        // per-row dot with eW2 slice; row = batch b, group g = node n.
        // gn = eW2 base, adjout = out_deltas (pre-initialized with eb2).
        const float* w2 = gn + (size_t)g * DD + n0;
        for (int row = wid; row < BM; row += NW) {
            float s = 0.f;
#pragma unroll
            for (int c2 = 0; c2 < BN/64; ++c2) {
                int col = lane * (BN/64) + c2;
                s += b2f(((const bf16*)Cs)[row*LDC + col]) * w2[col];
            }
#pragma unroll
            for (int m = 1; m < 64; m <<= 1) s += __shfl_xor(s, m, 64);
            if (lane == 0) atomicAdd(&adjout[(size_t)row * NN + g], s);
        }
    } else {
        // coalesced vector store: 16B per lane (+ optional fused adj)
        constexpr int VEC = 16 / sizeof(TC);
#pragma unroll
        for (int c = tid; c < BM*(BN/VEC); c += NT) {
            int row = c / (BN/VEC), col = (c % (BN/VEC)) * VEC;
            size_t gidx = (size_t)g*sCg + (size_t)(m0+row)*ldc + n0 + col;
            *(float4*)&C[gidx] = *(const float4*)&Cs[row*LDC + col];
            if constexpr (FUSE_ADJ) {
                float4 cv = *(const float4*)&Cs[row*LDC + col];
                float4 g4 = *(const float4*)&gn[gidx];
                float4 a4;
                a4.x = 1.0f / (1.0f + __expf(-(cv.x + g4.x)));
                a4.y = 1.0f / (1.0f + __expf(-(cv.y + g4.y)));
                a4.z = 1.0f / (1.0f + __expf(-(cv.z + g4.z)));
                a4.w = 1.0f / (1.0f + __expf(-(cv.w + g4.w)));
                *(float4*)&adjout[gidx] = a4;
            }
        }
    }
}

// ---------------- MFMA fused attention on packed QKV [8192][1536] ----------
// K staged in LDS (shared across the 4 waves); V^T staged; O via Ps re-use.
__global__ __launch_bounds__(256) void attn_mfma(bf16* __restrict__ QKV)
{
    __shared__ bf16 Ps[NN][NN + 8];
    __shared__ bf16 Ks[NN][DHH + 8];
    __shared__ bf16 Vt[DHH][NN + 8];
    int bh = blockIdx.x;
    int h = bh & (HH - 1);
    int b = bh >> 3;
    const int tid = threadIdx.x;
    const int lane = tid & 63;
    const int w = tid >> 6;
    const int lr = lane & 15;
    const int lq = lane >> 4;
    const size_t baseQ = (size_t)(b * NN) * LDQKV + h * DHH;
    const size_t baseK = baseQ + 512;
    const size_t baseV = baseQ + 1024;

    for (int c = tid; c < NN * (DHH/8); c += 256) {
        int row = c >> 3, d8 = (c & 7) * 8;
        *(float4*)&Ks[row][d8] =
            *(const float4*)(QKV + baseK + (size_t)row * LDQKV + d8);
    }
    for (int c = tid; c < 512; c += 256) {
        int m = (c >> 3) * 2;
        int d8 = (c & 7) * 8;
        F4B8 v0, v1;
        v0.f = *(const float4*)(QKV + baseV + (size_t)m * LDQKV + d8);
        v1.f = *(const float4*)(QKV + baseV + (size_t)(m + 1) * LDQKV + d8);
#pragma unroll
        for (int j = 0; j < 8; j++) {
            B2U pk; pk.h[0] = v0.h[j]; pk.h[1] = v1.h[j];
            *(unsigned int*)&Vt[d8 + j][m] = pk.u;
        }
    }
    __syncthreads();

    f32x4v sacc[2][8];
#pragma unroll
    for (int mi = 0; mi < 2; mi++)
#pragma unroll
        for (int ni = 0; ni < 8; ni++)
            sacc[mi][ni] = (f32x4v){0.f, 0.f, 0.f, 0.f};
#pragma unroll
    for (int ks = 0; ks < 2; ks++) {
        short8v aq[2];
#pragma unroll
        for (int mi = 0; mi < 2; mi++) {
            int row = w * 32 + mi * 16 + lr;
            aq[mi] = *(const short8v*)(QKV + baseQ + (size_t)row * LDQKV + ks * 32 + lq * 8);
        }
#pragma unroll
        for (int ni = 0; ni < 8; ni++) {
            short8v bk = *(const short8v*)&Ks[ni * 16 + lr][ks * 32 + lq * 8];
#pragma unroll
            for (int mi = 0; mi < 2; mi++)
                sacc[mi][ni] = __builtin_amdgcn_mfma_f32_16x16x32_bf16(
                    aq[mi], bk, sacc[mi][ni], 0, 0, 0);
        }
    }

#pragma unroll
    for (int mi = 0; mi < 2; mi++) {
#pragma unroll
        for (int r = 0; r < 4; r++) {
            float mx = -1e30f;
#pragma unroll
            for (int ni = 0; ni < 8; ni++)
                mx = fmaxf(mx, sacc[mi][ni][r]);
            mx = fmaxf(mx, __shfl_xor(mx, 1, 64));
            mx = fmaxf(mx, __shfl_xor(mx, 2, 64));
            mx = fmaxf(mx, __shfl_xor(mx, 4, 64));
            mx = fmaxf(mx, __shfl_xor(mx, 8, 64));
            mx *= 0.125f;
            float s = 0.f;
#pragma unroll
            for (int ni = 0; ni < 8; ni++) {
                float e = __expf(sacc[mi][ni][r] * 0.125f - mx);
                sacc[mi][ni][r] = e; s += e;
            }
            s += __shfl_xor(s, 1, 64);
            s += __shfl_xor(s, 2, 64);
            s += __shfl_xor(s, 4, 64);
            s += __shfl_xor(s, 8, 64);
            float inv = 1.0f / s;
            int row = w * 32 + mi * 16 + lq * 4 + r;
#pragma unroll
            for (int ni = 0; ni < 8; ni++)
                Ps[row][ni * 16 + lr] = f2b(sacc[mi][ni][r] * inv);
        }
    }
    __syncthreads();

    f32x4v oacc[2][4];
#pragma unroll
    for (int mi = 0; mi < 2; mi++)
#pragma unroll
        for (int ni = 0; ni < 4; ni++)
            oacc[mi][ni] = (f32x4v){0.f, 0.f, 0.f, 0.f};
#pragma unroll
    for (int ks = 0; ks < 4; ks++) {
        short8v ap[2];
#pragma unroll
        for (int mi = 0; mi < 2; mi++)
            ap[mi] = *(const short8v*)&Ps[w * 32 + mi * 16 + lr][ks * 32 + lq * 8];
#pragma unroll
        for (int ni = 0; ni < 4; ni++) {
            short8v bv = *(const short8v*)&Vt[ni * 16 + lr][ks * 32 + lq * 8];
#pragma unroll
            for (int mi = 0; mi < 2; mi++)
                oacc[mi][ni] = __builtin_amdgcn_mfma_f32_16x16x32_bf16(
                    ap[mi], bv, oacc[mi][ni], 0, 0, 0);
        }
    }
    __syncthreads();           // Ps fragment reads done — reuse Ps as O tile
#pragma unroll
    for (int mi = 0; mi < 2; mi++)
#pragma unroll
        for (int ni = 0; ni < 4; ni++) {
            int d = ni * 16 + lr;
#pragma unroll
            for (int r = 0; r < 4; r++) {
                int row = w * 32 + mi * 16 + lq * 4 + r;
                Ps[row][d] = f2b(oacc[mi][ni][r]);
            }
        }
    __syncthreads();
    for (int c = tid; c < NN * (DHH/8); c += 256) {
        int row = c >> 3, d8 = (c & 7) * 8;
        *(float4*)(QKV + baseQ + (size_t)row * LDQKV + d8) = *(const float4*)&Ps[row][d8];
    }
}

// ---------------- add+LN: one wave per token; R has stride ldr ------------
__global__ __launch_bounds__(256) void add_ln_kernel(
    bf16* __restrict__ X, const bf16* __restrict__ R, int ldr,
    const float* __restrict__ g, const float* __restrict__ bt)
{
    int tok = blockIdx.x * 4 + (threadIdx.x >> 6);
    int lane = threadIdx.x & 63;
    size_t base = (size_t)tok * DD + lane * 8;
    size_t rbase = (size_t)tok * ldr + lane * 8;
    F4B8 x, r;
    x.f = *(const float4*)&X[base];
    r.f = *(const float4*)&R[rbase];
    float v[8]; float s = 0.f, s2 = 0.f;
#pragma unroll
    for (int j = 0; j < 8; j++) {
        v[j] = b2f(x.h[j]) + b2f(r.h[j]);
        s += v[j]; s2 += v[j] * v[j];
    }
#pragma unroll
    for (int m = 1; m < 64; m <<= 1) {
        s  += __shfl_xor(s, m, 64);
        s2 += __shfl_xor(s2, m, 64);
    }
    float mean = s * (1.0f / 512.0f);
    float var = fmaxf(s2 * (1.0f / 512.0f) - mean * mean, 0.0f);
    float rstd = rsqrtf(var + 1e-5f);
    alignas(16) float gv[8], bv[8];
    *(float4*)&gv[0] = *(const float4*)&g[lane * 8];
    *(float4*)&gv[4] = *(const float4*)&g[lane * 8 + 4];
    *(float4*)&bv[0] = *(const float4*)&bt[lane * 8];
    *(float4*)&bv[4] = *(const float4*)&bt[lane * 8 + 4];
    F4B8 o;
#pragma unroll
    for (int j = 0; j < 8; j++)
        o.h[j] = f2b((v[j] - mean) * rstd * gv[j] + bv[j]);
    *(float4*)&X[base] = o.f;
}

// ---------------- hyper-network ----------------
__global__ __launch_bounds__(512) void hyper_kernel(
    const int* __restrict__ idx, const float* __restrict__ emb,
    const float* __restrict__ W1, const float* __restrict__ b1,
    const float* __restrict__ W2, const float* __restrict__ b2,
    float* __restrict__ MODp)
{
    int b = blockIdx.x;
    int t = threadIdx.x;
    __shared__ float instr[EE];
    __shared__ float h1[HID];
    int id = idx[b];
    if (t < EE) instr[t] = emb[id*EE + t];
    __syncthreads();
    if (t < HID) {
        float a = b1[t];
        for (int i = 0; i < EE; i++) a += instr[i] * W1[i*HID + t];
        h1[t] = gelu_f(a);
    }
    __syncthreads();
    float a = b2[t];
    for (int i = 0; i < HID; i++) a += h1[i] * W2[i*DD + t];
    MODp[(size_t)b*DD + t] = a;
}

// ---------------- host-side GEMM dispatch helper ----------------
template<int BM,int BN,int WM,int WN,int ACT,bool HB,typename TC>
static inline void launch2(bool useT, dim3 grid, hipStream_t s,
    const bf16* A, const float* Wf, const bf16* Wt, const float* bias, TC* C,
    int K, int lda, int ldbF, int ldbT, int ldc,
    long long sAg, long long sBg, long long sbg, long long sCg)
{
    if (useT)
        gemm2<BM,BN,WM,WN,ACT,true ,HB,false,false,false,bf16 ,TC><<<grid,WM*WN*64,0,s>>>(
            A, Wt, bias, C, K, lda, ldbT, ldc, sAg,sBg,sbg,sCg,
            nullptr, nullptr, nullptr);
    else
        gemm2<BM,BN,WM,WN,ACT,false,HB,false,false,false,float,TC><<<grid,WM*WN*64,0,s>>>(
            A, Wf, bias, C, K, lda, ldbF, ldc, sAg,sBg,sbg,sCg,
            nullptr, nullptr, nullptr);
}

// =========================== host side ===========================
extern "C" void kernel_launch(void* const* d_in, const int* in_sizes, int n_in,
                              void* d_out, int out_size, void* d_ws, size_t ws_size,
                              hipStream_t stream)
{
    const float* base_s = (const float*)d_in[0];
    const float* int_s  = (const float*)d_in[1];
    const float* targ   = (const float*)d_in[2];
    const float* maskv  = (const float*)d_in[3];
    const int*   nidx   = (const int*)  d_in[4];
    const float* gnoise = (const float*)d_in[5];
    const float* encW = (const float*)d_in[6];
    const float* encB = (const float*)d_in[7];
    const float* Wq = (const float*)d_in[8];  const float* bq = (const float*)d_in[9];
    const float* Wk = (const float*)d_in[10]; const float* bk = (const float*)d_in[11];
    const float* Wv = (const float*)d_in[12]; const float* bv = (const float*)d_in[13];
    const float* Wo = (const float*)d_in[14]; const float* bo = (const float*)d_in[15];
    const float* ln1g = (const float*)d_in[16]; const float* ln1b = (const float*)d_in[17];
    const float* Wff1 = (const float*)d_in[18]; const float* bff1 = (const float*)d_in[19];
    const float* Wff2 = (const float*)d_in[20]; const float* bff2 = (const float*)d_in[21];
    const float* ln2g = (const float*)d_in[22]; const float* ln2b = (const float*)d_in[23];
    const float* emb  = (const float*)d_in[24];
    const float* hW1 = (const float*)d_in[25]; const float* hb1 = (const float*)d_in[26];
    const float* hW2 = (const float*)d_in[27]; const float* hb2 = (const float*)d_in[28];
    const float* eW1 = (const float*)d_in[29]; const float* eb1 = (const float*)d_in[30];
    const float* eW2 = (const float*)d_in[31]; const float* eb2 = (const float*)d_in[32];
    const float* dpW = (const float*)d_in[33]; const float* dpB = (const float*)d_in[34];
    const float* dcW = (const float*)d_in[35]; const float* dcB = (const float*)d_in[36];

    float* out_deltas = (float*)d_out;
    float* out_logits = out_deltas + (size_t)BB*NN;
    float* out_adj    = out_logits + (size_t)BB*NN*NN;

    const size_t SZ = (size_t)NTOK * DD;     // 4,194,304 elements

    const size_t WT_ELEMS = (size_t)3*LL*DD*DD + (size_t)LL*DD*DD
                          + 2*(size_t)LL*DD*DFF + 2*(size_t)DD*DD;  // 13,107,200
    const size_t NEED_BIG = 6*SZ*2 + (size_t)BB*DD*4;
    const size_t NEED_P0  = NEED_BIG + WT_ELEMS*2 + (LL*LDQKV + 1024)*4;
    const bool big = ws_size >= NEED_BIG;
    const bool p0  = ws_size >= NEED_P0;

    bf16* X  = (bf16*)d_ws;
    bf16* PK = X + SZ;                 // packed QKV / Hid / DAG / scratch
    bf16* F2 = PK + 4*SZ;              // big only
    float* MODp = big ? (float*)(F2 + SZ) : (float*)(PK + 3*SZ);

    bf16 *wqkvT=nullptr,*woT=nullptr,*wf1T=nullptr,*wf2T=nullptr,*dagT=nullptr;
    float *qkvB=nullptr,*dagB=nullptr;
    if (p0) {
        bf16* WT = (bf16*)(MODp + (size_t)BB*DD);
        wqkvT = WT;                                 // [L][1536][512]
        woT   = wqkvT + (size_t)3*LL*DD*DD;         // [L][512][512]
        wf1T  = woT + (size_t)LL*DD*DD;             // [L][2048][512]
        wf2T  = wf1T + (size_t)LL*DD*DFF;           // [L][512][2048]
        dagT  = wf2T + (size_t)LL*DD*DFF;           // [1024][512]
        qkvB  = (float*)(dagT + 2*(size_t)DD*DD);
        dagB  = qkvB + LL*LDQKV;

        TXJobs J;
        int acc = 0;
        auto addjob = [&](int j, const float* in, bf16* out, int K, int N,
                          long long sIn, long long sOut, int G) {
            J.in[j]=in; J.out[j]=out; J.K[j]=K; J.N[j]=N; J.sIn[j]=sIn; J.sOut[j]=sOut;
            acc += G * (K>>5) * (N>>5); J.tileEnd[j]=acc;
        };
        addjob(0, Wq,  wqkvT,          DD, DD, (long long)DD*DD, (long long)LDQKV*DD, LL);
        addjob(1, Wk,  wqkvT+512*512,  DD, DD, (long long)DD*DD, (long long)LDQKV*DD, LL);
        addjob(2, Wv,  wqkvT+1024*512, DD, DD, (long long)DD*DD, (long long)LDQKV*DD, LL);
        addjob(3, Wo,  woT,            DD, DD, (long long)DD*DD, (long long)DD*DD,    LL);
        addjob(4, Wff1,wf1T,           DD, DFF,(long long)DD*DFF,(long long)DD*DFF,   LL);
        addjob(5, Wff2,wf2T,           DFF,DD, (long long)DD*DFF,(long long)DD*DFF,   LL);
        addjob(6, dpW, dagT,           DD, DD, 0, 0, 1);
        addjob(7, dcW, dagT+512*512,   DD, DD, 0, 0, 1);
        transpose_all<<<acc, 256, 0, stream>>>(J);
        pack_bias<<<(LL*LDQKV + 1024 + 255)/256, 256, 0, stream>>>(
            bq, bk, bv, dpB, dcB, qkvB, dagB);
    }

    encoder_kernel<<<NTOK*DD/8/256, 256, 0, stream>>>(
        base_s, int_s, targ, maskv, encW, encB, X);

    for (int l = 0; l < LL; ++l) {
        const size_t od = (size_t)l*DD*DD, of1 = (size_t)l*DD*DFF;
        // QKV -> packed PK [8192][1536]
        if (p0) {
            gemm2<128,128,2,4,0,true,true,false,false,false,bf16,bf16><<<dim3(12,64,1),512,0,stream>>>(
                X, wqkvT + (size_t)l*LDQKV*DD, qkvB + (size_t)l*LDQKV, PK,
                DD, DD, DD, LDQKV, 0,0,0,0, nullptr, nullptr, nullptr);
        } else {
            gemm2<128,128,2,4,0,false,true,false,false,false,float,bf16><<<dim3(4,64,1),512,0,stream>>>(
                X, Wq+od, bq+(size_t)l*DD, PK,        DD, DD, DD, LDQKV, 0,0,0,0,
                nullptr, nullptr, nullptr);
            gemm2<128,128,2,4,0,false,true,false,false,false,float,bf16><<<dim3(4,64,1),512,0,stream>>>(
                X, Wk+od, bk+(size_t)l*DD, PK+512,    DD, DD, DD, LDQKV, 0,0,0,0,
                nullptr, nullptr, nullptr);
            gemm2<128,128,2,4,0,false,true,false,false,false,float,bf16><<<dim3(4,64,1),512,0,stream>>>(
                X, Wv+od, bv+(size_t)l*DD, PK+1024,   DD, DD, DD, LDQKV, 0,0,0,0,
                nullptr, nullptr, nullptr);
        }
        attn_mfma<<<BB*HH, 256, 0, stream>>>(PK);   // O in place over Q slice
        // O-proj: BM=64 -> grid (4,128)=512 blocks (2 blocks/CU)
        launch2<64,128,2,4,0,true,bf16>(p0, dim3(4,128,1), stream,
            PK, Wo+od, woT+od, bo+(size_t)l*DD, PK+512, DD, LDQKV, DD, DD, LDQKV, 0,0,0,0);
        add_ln_kernel<<<NTOK/4, 256, 0, stream>>>(X, PK+512, LDQKV,
            ln1g+(size_t)l*DD, ln1b+(size_t)l*DD);

        if (big) {
            launch2<128,128,2,4,1,true,bf16>(p0, dim3(16,64,1), stream,
                X, Wff1+of1, wf1T+of1, bff1+(size_t)l*DFF, PK,
                DD, DD, DFF, DD, DFF, 0,0,0,0);
            // FFN2: BM=64 -> grid (4,128)=512 blocks (2 blocks/CU)
            launch2<64,128,2,4,0,true,bf16>(p0, dim3(4,128,1), stream,
                PK, Wff2+of1, wf2T+of1, bff2+(size_t)l*DD, F2,
                DFF, DFF, DD, DFF, DD, 0,0,0,0);
            add_ln_kernel<<<NTOK/4, 256, 0, stream>>>(X, F2, DD,
                ln2g+(size_t)l*DD, ln2b+(size_t)l*DD);
        } else {
            for (int c = 0; c < 4; ++c) {
                launch2<128,128,2,4,1,true,bf16>(p0, dim3(16,16,1), stream,
                    X + (size_t)c*2048*DD, Wff1+of1, wf1T+of1, bff1+(size_t)l*DFF, PK,
                    DD, DD, DFF, DD, DFF, 0,0,0,0);
                launch2<64,128,2,4,0,true,bf16>(p0, dim3(4,32,1), stream,
                    PK, Wff2+of1, wf2T+of1, bff2+(size_t)l*DD, PK + 2*SZ + (size_t)c*2048*DD,
                    DFF, DFF, DD, DFF, DD, 0,0,0,0);
            }
            add_ln_kernel<<<NTOK/4, 256, 0, stream>>>(X, PK + 2*SZ, DD,
                ln2g+(size_t)l*DD, ln2b+(size_t)l*DD);
        }
    }

    hyper_kernel<<<BB, 512, 0, stream>>>(nidx, emb, hW1, hb1, hW2, hb2, MODp);

    // deltas = eb2 (init), then expert GEMM fuses xm (ASCALE) + row-dot with
    // eW2 (FUSE_DELTA, atomicAdd) — HE never hits global memory.
    deltas_init<<<(BB*NN + 255)/256, 256, 0, stream>>>(eb2, out_deltas);
    gemm2<64,128,2,2,1,false,true,true,false,true,float,bf16><<<dim3(4,1,NN),256,0,stream>>>(
        X, eW1, eb1, (bf16*)PK /*unused*/, DD, NN*DD, DD, DD,
        DD, (long long)DD*DD, DD, (long long)BB*DD, MODp, eW2, out_deltas);

    // DAG heads -> packed [8192][1024] in PK
    bf16* DAGb = PK;
    if (p0) {
        gemm2<128,128,2,4,0,true,true,false,false,false,bf16,bf16><<<dim3(8,64,1),512,0,stream>>>(
            X, dagT, dagB, DAGb, DD, DD, DD, 1024, 0,0,0,0, nullptr, nullptr, nullptr);
    } else {
        gemm2<128,128,2,4,0,false,true,false,false,false,float,bf16><<<dim3(4,64,1),512,0,stream>>>(
            X, dpW, dpB, DAGb,       DD, DD, DD, 1024, 0,0,0,0, nullptr, nullptr, nullptr);
        gemm2<128,128,2,4,0,false,true,false,false,false,float,bf16><<<dim3(4,64,1),512,0,stream>>>(
            X, dcW, dcB, DAGb + 512, DD, DD, DD, 1024, 0,0,0,0, nullptr, nullptr, nullptr);
    }
    // logits[b] = P[b] @ C[b]^T, f32 into d_out; adj fused in epilogue
    gemm2<64,64,2,2,0,true,false,false,true,false,bf16,float><<<dim3(2,2,BB),256,0,stream>>>(
        DAGb, DAGb + 512, (const float*)nullptr, out_logits,
        DD, 1024, 1024, NN,
        (long long)NN*1024, (long long)NN*1024, 0, (long long)NN*NN,
        nullptr, gnoise, out_adj);

    (void)in_sizes; (void)n_in; (void)out_size;
}